// Round 15
// baseline (1183.045 us; speedup 1.0000x reference)
//
#include <hip/hip_runtime.h>
#include <math.h>

#define N_NODES 50000
#define E_EDGES 1600000
#define F_INDIM 512
#define H_DIM   256
#define C_OUT   121
#define L_LAYERS 4

typedef unsigned short u16;
typedef short bf16x8 __attribute__((ext_vector_type(8)));
typedef float f32x4  __attribute__((ext_vector_type(4)));

__device__ __forceinline__ float bf2f(u16 h) {
    return __uint_as_float(((unsigned int)h) << 16);
}
__device__ __forceinline__ u16 f2bf(float f) {
    unsigned int u = __float_as_uint(f);
    unsigned int r = u + 0x7FFFu + ((u >> 16) & 1u);   // round-to-nearest-even
    return (u16)(r >> 16);
}

// ---------------- utility ----------------
__global__ void zeroi_kernel(int* __restrict__ p, int n) {
    int i = blockIdx.x * blockDim.x + threadIdx.x;
    if (i < n) p[i] = 0;
}

// single prep kernel: all weight transposes+bf16 conversion in one launch
// seg0 WT0[256][512] <- l0w[512][256]; seg1 WTc[4][256][256] <- cw; seg2 WT1[128][256] <- l1w[256][121]
__global__ void prep_kernel(const float* __restrict__ l0w, const float* __restrict__ cw,
                            const float* __restrict__ l1w, u16* __restrict__ WT0,
                            u16* __restrict__ WTc, u16* __restrict__ WT1) {
    int i = blockIdx.x * blockDim.x + threadIdx.x;
    if (i < 131072) {                       // 256*512
        int n = i >> 9, k = i & 511;
        WT0[i] = f2bf(l0w[(long)k * H_DIM + n]);
        return;
    }
    i -= 131072;
    if (i < 262144) {                       // 4*256*256
        int l = i >> 16, j = i & 65535, n = j >> 8, k = j & 255;
        WTc[(l << 16) + j] = f2bf(cw[(long)l * 65536 + (long)k * H_DIM + n]);
        return;
    }
    i -= 262144;
    if (i < 32768) {                        // 128*256
        int n = i >> 8, k = i & 255;
        WT1[i] = (n < C_OUT) ? f2bf(l1w[(long)k * C_OUT + n]) : (u16)0;
    }
}

// ---------------- CSR build ----------------
__global__ void hist_kernel(const int* __restrict__ dst, int* __restrict__ deg) {
    int e = blockIdx.x * blockDim.x + threadIdx.x;
    if (e < E_EDGES) {
        int d = dst[e];
        if (d >= 0 && d < N_NODES) atomicAdd(&deg[d], 1);
    }
}

// single block, 256 threads: exclusive scan; writes row_ptr AND seeds cnt with the
// row base so scatter's atomicAdd returns an absolute slot (drops 2nd zeroi launch)
__global__ void scan_kernel(int* cnt, int* __restrict__ row_ptr) {
    __shared__ int sums[256];
    const int t = threadIdx.x;
    const int CH = (N_NODES + 255) / 256;   // 196
    const int base = t * CH;
    int s = 0;
    for (int i = 0; i < CH; ++i) {
        int idx = base + i;
        if (idx < N_NODES) s += cnt[idx];
    }
    sums[t] = s;
    __syncthreads();
    for (int off = 1; off < 256; off <<= 1) {
        int v = (t >= off) ? sums[t - off] : 0;
        __syncthreads();
        sums[t] += v;
        __syncthreads();
    }
    int run = (t == 0) ? 0 : sums[t - 1];
    for (int i = 0; i < CH; ++i) {
        int idx = base + i;
        if (idx < N_NODES) {
            int dv = cnt[idx];
            row_ptr[idx] = run;
            cnt[idx] = run;     // seed for scatter
            run += dv;
        }
    }
    if (t == 255) row_ptr[N_NODES] = run;    // == E
}

__global__ void scatter_kernel(const int* __restrict__ src, const int* __restrict__ dst,
                               const float* __restrict__ w,
                               int* __restrict__ cnt, int* __restrict__ s_src,
                               float* __restrict__ s_w) {
    int e = blockIdx.x * blockDim.x + threadIdx.x;
    if (e < E_EDGES) {
        int d = dst[e];
        if (d < 0) d = 0; if (d >= N_NODES) d = N_NODES - 1;   // defensive
        long idx = atomicAdd(&cnt[d], 1);                      // absolute slot
        if (idx < 0) idx = 0; if (idx >= E_EDGES) idx = E_EDGES - 1;  // defensive
        s_src[idx] = src[e];
        s_w[idx]   = w[e];
    }
}

// ===== fused layer: gather(A@Xin) + combine -> LDS tile -> MFMA conv -> residual =====
// block = 16 dst rows (3125 blocks), 4 waves. Double-buffered Xin/Xout (R10 race fix).
// Phase 1 (R12 form — R14's 8-edge MLP regressed via occupancy, reverted): lane covers
//   16B (8 feats, q=l&31); wave halves process edges e+half, e+2+half -> 4 chains in
//   flight. Cross-half reduce via __shfl_xor(32); lanes 0-31 combine with X0 and
//   ds_write_b128 into swizzled LDS (byte(f) = f*2 ^ ((rl&7)<<4)).
// Phase 2: wave w computes cols [w*64,(w+1)*64) via 16x16x32 MFMA, K=256.
// Epilogue: v = relu((1-beta)*Hb + beta*acc + Xin); normally stored to Xout.
// LAST LAYER (outp != nullptr): v goes to xs LDS tile instead (bf16, same rounding),
//   then each wave MFMAs its 32-col slice of lin1 (K=256, WT1) and stores out+bias.
__global__ __launch_bounds__(256) void layer_kernel(
        const int* __restrict__ row_ptr, const int* __restrict__ s_src,
        const float* __restrict__ s_w, const u16* __restrict__ Xin,
        const u16* __restrict__ X0, u16* __restrict__ Xout,
        const u16* __restrict__ WT, float beta,
        const u16* __restrict__ WT1, const float* __restrict__ l1b,
        float* __restrict__ outp) {
    __shared__ __align__(16) u16 hs[16 * H_DIM];   // 8 KB, byte-swizzled
    __shared__ __align__(16) u16 xs[16 * H_DIM];   // 8 KB, last-layer X tile
    const int w  = threadIdx.x >> 6;
    const int l  = threadIdx.x & 63;
    const int hi = l >> 4, lo = l & 15;
    const int half = l >> 5;          // 0|1: which edge of the pair
    const int q    = l & 31;          // 16B chunk index within the 512B row
    const int bm = blockIdx.x * 16;

    // ---- phase 1: gather 4 rows per wave, 4 edges in flight ----
    for (int i = 0; i < 4; ++i) {
        const int rl  = w * 4 + i;
        const int row = bm + rl;
        int beg = row_ptr[row], end = row_ptr[row + 1];
        if (beg < 0) beg = 0; if (end > E_EDGES) end = E_EDGES;   // defensive
        float accA[8] = {}, accB[8] = {};
        for (int e = beg; e < end; e += 4) {
            const int eA = e + half;
            const int eB = e + 2 + half;
            const int cA = (eA < end) ? eA : end - 1;   // end-1 >= beg >= 0 here
            const int cB = (eB < end) ? eB : end - 1;
            float wA = (eA < end) ? s_w[cA] : 0.f;
            float wB = (eB < end) ? s_w[cB] : 0.f;
            int sA = s_src[cA]; if (sA < 0) sA = 0; if (sA >= N_NODES) sA = N_NODES - 1;
            int sB = s_src[cB]; if (sB < 0) sB = 0; if (sB >= N_NODES) sB = N_NODES - 1;
            bf16x8 vA = *reinterpret_cast<const bf16x8*>(Xin + (long)sA * H_DIM + q * 8);
            bf16x8 vB = *reinterpret_cast<const bf16x8*>(Xin + (long)sB * H_DIM + q * 8);
            #pragma unroll
            for (int j = 0; j < 8; ++j) {
                accA[j] += wA * bf2f((u16)vA[j]);
                accB[j] += wB * bf2f((u16)vB[j]);
            }
        }
        float acc[8];
        #pragma unroll
        for (int j = 0; j < 8; ++j) {
            float s = accA[j] + accB[j];
            s += __shfl_xor(s, 32);
            acc[j] = s;
        }
        if (l < 32) {
            bf16x8 x0 = *reinterpret_cast<const bf16x8*>(X0 + (long)row * H_DIM + q * 8);
            bf16x8 ov;
            #pragma unroll
            for (int j = 0; j < 8; ++j)
                ov[j] = (short)f2bf(0.5f * acc[j] + 0.5f * bf2f((u16)x0[j]));
            const int off = rl * 512 + ((q * 16) ^ ((rl & 7) << 4));   // 16B-aligned
            *reinterpret_cast<bf16x8*>((char*)hs + off) = ov;
        }
    }
    __syncthreads();

    // ---- phase 2: conv GEMM on the LDS tile ----
    const int col0 = w * 64;
    f32x4 acc[4];
    #pragma unroll
    for (int t = 0; t < 4; ++t) acc[t] = (f32x4){0.f, 0.f, 0.f, 0.f};

    for (int k0 = 0; k0 < H_DIM; k0 += 32) {
        const int aoff = lo * 512 + (((k0 * 2) + hi * 16) ^ ((lo & 7) << 4));  // 16B-aligned
        bf16x8 a = *reinterpret_cast<const bf16x8*>((const char*)hs + aoff);
        #pragma unroll
        for (int t = 0; t < 4; ++t) {
            bf16x8 b = *reinterpret_cast<const bf16x8*>(
                    WT + (long)(col0 + t * 16 + lo) * H_DIM + k0 + hi * 8);
            acc[t] = __builtin_amdgcn_mfma_f32_16x16x32_bf16(a, b, acc[t], 0, 0, 0);
        }
    }

    // ---- epilogue: residual + relu -> Xout (or xs tile for fused lin1) ----
    #pragma unroll
    for (int t = 0; t < 4; ++t) {
        const int col = col0 + t * 16 + lo;
        #pragma unroll
        for (int r = 0; r < 4; ++r) {
            const int rl  = hi * 4 + r;
            const int row = bm + rl;
            const int hoff = rl * 512 + ((col * 2) ^ ((rl & 7) << 4));
            float hv = bf2f(*reinterpret_cast<const u16*>((const char*)hs + hoff));
            long idx = (long)row * H_DIM + col;
            float v = (1.f - beta) * hv + beta * acc[t][r] + bf2f(Xin[idx]);
            u16 vb = f2bf(fmaxf(v, 0.f));
            if (outp == nullptr) {
                Xout[idx] = vb;
            } else {
                *reinterpret_cast<u16*>((char*)xs + hoff) = vb;   // same swizzled layout
            }
        }
    }

    // ---- fused lin1 (last layer only): out = Xfinal @ WT1^T + l1b ----
    if (outp != nullptr) {
        __syncthreads();
        const int c1 = w * 32;
        f32x4 acc2[2];
        acc2[0] = (f32x4){0.f, 0.f, 0.f, 0.f};
        acc2[1] = (f32x4){0.f, 0.f, 0.f, 0.f};
        for (int k0 = 0; k0 < H_DIM; k0 += 32) {
            const int aoff = lo * 512 + (((k0 * 2) + hi * 16) ^ ((lo & 7) << 4));
            bf16x8 a = *reinterpret_cast<const bf16x8*>((const char*)xs + aoff);
            #pragma unroll
            for (int t = 0; t < 2; ++t) {
                bf16x8 b = *reinterpret_cast<const bf16x8*>(
                        WT1 + (long)(c1 + t * 16 + lo) * H_DIM + k0 + hi * 8);
                acc2[t] = __builtin_amdgcn_mfma_f32_16x16x32_bf16(a, b, acc2[t], 0, 0, 0);
            }
        }
        #pragma unroll
        for (int t = 0; t < 2; ++t) {
            const int col = c1 + t * 16 + lo;
            if (col < C_OUT) {
                const float bias = l1b[col];
                #pragma unroll
                for (int r = 0; r < 4; ++r) {
                    const int row = bm + hi * 4 + r;
                    outp[(long)row * C_OUT + col] = acc2[t][r] + bias;
                }
            }
        }
    }
}

// ---------------- MFMA GEMM (lin0 only) ----------------
// A fp32; X=X0=relu(acc+bias)
template <int K, int NT>
__global__ __launch_bounds__(256) void mfma_gemm_kernel(
        const float* __restrict__ Aptr, const u16* __restrict__ WT,
        const float* __restrict__ bias,
        u16* __restrict__ X, u16* __restrict__ X0) {
    const int w  = threadIdx.x >> 6;
    const int l  = threadIdx.x & 63;
    const int hi = l >> 4, lo = l & 15;
    const int bm = blockIdx.x * 16;
    const int col0 = w * (NT * 16);

    f32x4 acc[NT];
    #pragma unroll
    for (int t = 0; t < NT; ++t) acc[t] = (f32x4){0.f, 0.f, 0.f, 0.f};

    for (int k0 = 0; k0 < K; k0 += 32) {
        bf16x8 a;
        const float* ap = Aptr + (long)(bm + lo) * K + k0 + hi * 8;
        float4 f0 = *reinterpret_cast<const float4*>(ap);
        float4 f1 = *reinterpret_cast<const float4*>(ap + 4);
        a[0] = (short)f2bf(f0.x); a[1] = (short)f2bf(f0.y);
        a[2] = (short)f2bf(f0.z); a[3] = (short)f2bf(f0.w);
        a[4] = (short)f2bf(f1.x); a[5] = (short)f2bf(f1.y);
        a[6] = (short)f2bf(f1.z); a[7] = (short)f2bf(f1.w);
        #pragma unroll
        for (int t = 0; t < NT; ++t) {
            bf16x8 b = *reinterpret_cast<const bf16x8*>(
                    WT + (long)(col0 + t * 16 + lo) * K + k0 + hi * 8);
            acc[t] = __builtin_amdgcn_mfma_f32_16x16x32_bf16(a, b, acc[t], 0, 0, 0);
        }
    }

    #pragma unroll
    for (int t = 0; t < NT; ++t) {
        const int col = col0 + t * 16 + lo;
        #pragma unroll
        for (int r = 0; r < 4; ++r) {
            const int row = bm + hi * 4 + r;
            float v = fmaxf(acc[t][r] + bias[col], 0.f);
            u16 h = f2bf(v);
            long idx = (long)row * H_DIM + col;
            X[idx] = h; X0[idx] = h;
        }
    }
}

extern "C" void kernel_launch(void* const* d_in, const int* in_sizes, int n_in,
                              void* d_out, int out_size, void* d_ws, size_t ws_size,
                              hipStream_t stream) {
    const float* x_in = (const float*)d_in[0];
    const int*   esrc = (const int*)d_in[1];
    const int*   edst = (const int*)d_in[2];
    const float* ew   = (const float*)d_in[3];
    const float* l0w  = (const float*)d_in[4];
    const float* l0b  = (const float*)d_in[5];
    const float* cw   = (const float*)d_in[6];
    const float* l1w  = (const float*)d_in[7];
    const float* l1b  = (const float*)d_in[8];
    float* out = (float*)d_out;
    (void)in_sizes; (void)n_in; (void)out_size;

    char* ws = (char*)d_ws;
    auto al = [](size_t x) { return (x + 255) & ~(size_t)255; };
    size_t o = 0;
    const size_t NHb = (size_t)N_NODES * H_DIM * sizeof(u16);    // 25.6 MB
    u16* Xa = (u16*)(ws + o);  o += al(NHb);
    u16* Xb = (u16*)(ws + o);  o += al(NHb);
    u16* X0 = (u16*)(ws + o);  o += al(NHb);
    int* row_ptr = (int*)(ws + o); o += al((N_NODES + 1) * sizeof(int));
    int* cnt     = (int*)(ws + o); o += al((size_t)N_NODES * sizeof(int));
    int* s_src   = (int*)(ws + o); o += al((size_t)E_EDGES * sizeof(int));
    float* s_w   = (float*)(ws + o); o += al((size_t)E_EDGES * sizeof(float));
    u16* WT0 = (u16*)(ws + o); o += al((size_t)H_DIM * F_INDIM * sizeof(u16));          // 256 KB
    u16* WTc = (u16*)(ws + o); o += al((size_t)L_LAYERS * H_DIM * H_DIM * sizeof(u16)); // 512 KB
    u16* WT1 = (u16*)(ws + o); o += al((size_t)128 * H_DIM * sizeof(u16));              // 64 KB
    if (ws_size < o) return;   // diagnostic: clean zero-output => ws too small

    const int MBLK = N_NODES / 16;   // 3125, exact

    // 0. weight prep (single launch: 426k elems / 256 = 1664 blocks)
    prep_kernel<<<1664, 256, 0, stream>>>(l0w, cw, l1w, WT0, WTc, WT1);

    // 1. input projection: Xa = X0 = relu(x_in @ l0w + l0b)   [MFMA]
    mfma_gemm_kernel<F_INDIM, 4><<<MBLK, 256, 0, stream>>>(x_in, WT0, l0b, Xa, X0);

    // 2. CSR build (4 launches: zero, hist, scan-with-seed, scatter)
    zeroi_kernel<<<(N_NODES + 255) / 256, 256, 0, stream>>>(cnt, N_NODES);
    hist_kernel<<<(E_EDGES + 255) / 256, 256, 0, stream>>>(edst, cnt);
    scan_kernel<<<1, 256, 0, stream>>>(cnt, row_ptr);
    scatter_kernel<<<(E_EDGES + 255) / 256, 256, 0, stream>>>(esrc, edst, ew,
                                                              cnt, s_src, s_w);

    // 3. fused layers, ping-pong Xa <-> Xb; last layer fuses lin1
    u16* Xcur = Xa;
    u16* Xnxt = Xb;
    for (int l = 0; l < L_LAYERS; ++l) {
        float beta = logf(1.0f / (float)(l + 1) + 1.0f);
        const bool last = (l == L_LAYERS - 1);
        layer_kernel<<<MBLK, 256, 0, stream>>>(
            row_ptr, s_src, s_w, Xcur, X0, Xnxt,
            WTc + (size_t)l * H_DIM * H_DIM, beta,
            last ? WT1 : nullptr, last ? l1b : nullptr, last ? out : nullptr);
        u16* tmp = Xcur; Xcur = Xnxt; Xnxt = tmp;
    }
}

// Round 17
// 1126.776 us; speedup vs baseline: 1.0499x; 1.0499x over previous
//
#include <hip/hip_runtime.h>
#include <math.h>

#define N_NODES 50000
#define E_EDGES 1600000
#define F_INDIM 512
#define H_DIM   256
#define C_OUT   121
#define L_LAYERS 4

typedef unsigned short u16;
typedef short bf16x8 __attribute__((ext_vector_type(8)));
typedef float f32x4  __attribute__((ext_vector_type(4)));

__device__ __forceinline__ float bf2f(u16 h) {
    return __uint_as_float(((unsigned int)h) << 16);
}
__device__ __forceinline__ u16 f2bf(float f) {
    unsigned int u = __float_as_uint(f);
    unsigned int r = u + 0x7FFFu + ((u >> 16) & 1u);   // round-to-nearest-even
    return (u16)(r >> 16);
}

// ---------------- utility ----------------
__global__ void zeroi_kernel(int* __restrict__ p, int n) {
    int i = blockIdx.x * blockDim.x + threadIdx.x;
    if (i < n) p[i] = 0;
}

// single prep kernel: all weight transposes+bf16 conversion in one launch
__global__ void prep_kernel(const float* __restrict__ l0w, const float* __restrict__ cw,
                            const float* __restrict__ l1w, u16* __restrict__ WT0,
                            u16* __restrict__ WTc, u16* __restrict__ WT1) {
    int i = blockIdx.x * blockDim.x + threadIdx.x;
    if (i < 131072) {                       // 256*512
        int n = i >> 9, k = i & 511;
        WT0[i] = f2bf(l0w[(long)k * H_DIM + n]);
        return;
    }
    i -= 131072;
    if (i < 262144) {                       // 4*256*256
        int l = i >> 16, j = i & 65535, n = j >> 8, k = j & 255;
        WTc[(l << 16) + j] = f2bf(cw[(long)l * 65536 + (long)k * H_DIM + n]);
        return;
    }
    i -= 262144;
    if (i < 32768) {                        // 128*256
        int n = i >> 8, k = i & 255;
        WT1[i] = (n < C_OUT) ? f2bf(l1w[(long)k * C_OUT + n]) : (u16)0;
    }
}

// ---------------- CSR build ----------------
__global__ void hist_kernel(const int* __restrict__ dst, int* __restrict__ deg) {
    int e = blockIdx.x * blockDim.x + threadIdx.x;
    if (e < E_EDGES) {
        int d = dst[e];
        if (d >= 0 && d < N_NODES) atomicAdd(&deg[d], 1);
    }
}

// single block, 256 threads: exclusive scan; writes row_ptr AND seeds cnt with the
// row base so scatter's atomicAdd returns an absolute slot
__global__ void scan_kernel(int* cnt, int* __restrict__ row_ptr) {
    __shared__ int sums[256];
    const int t = threadIdx.x;
    const int CH = (N_NODES + 255) / 256;   // 196
    const int base = t * CH;
    int s = 0;
    for (int i = 0; i < CH; ++i) {
        int idx = base + i;
        if (idx < N_NODES) s += cnt[idx];
    }
    sums[t] = s;
    __syncthreads();
    for (int off = 1; off < 256; off <<= 1) {
        int v = (t >= off) ? sums[t - off] : 0;
        __syncthreads();
        sums[t] += v;
        __syncthreads();
    }
    int run = (t == 0) ? 0 : sums[t - 1];
    for (int i = 0; i < CH; ++i) {
        int idx = base + i;
        if (idx < N_NODES) {
            int dv = cnt[idx];
            row_ptr[idx] = run;
            cnt[idx] = run;     // seed for scatter
            run += dv;
        }
    }
    if (t == 255) row_ptr[N_NODES] = run;    // == E
}

__global__ void scatter_kernel(const int* __restrict__ src, const int* __restrict__ dst,
                               const float* __restrict__ w,
                               int* __restrict__ cnt, int* __restrict__ s_src,
                               float* __restrict__ s_w) {
    int e = blockIdx.x * blockDim.x + threadIdx.x;
    if (e < E_EDGES) {
        int d = dst[e];
        if (d < 0) d = 0; if (d >= N_NODES) d = N_NODES - 1;   // defensive
        long idx = atomicAdd(&cnt[d], 1);                      // absolute slot
        if (idx < 0) idx = 0; if (idx >= E_EDGES) idx = E_EDGES - 1;  // defensive
        s_src[idx] = src[e];
        s_w[idx]   = w[e];
    }
}

// ===== fused layer: gather(A@Xin) + combine -> LDS tile -> MFMA conv -> residual =====
// block = 16 dst rows (3125 blocks), 4 waves. Double-buffered Xin/Xout (R10 race fix).
// LDS: ONE 8 KB tile (R15's separate 16KB xs cost 10% occupancy -> 195us; reverted).
// Phase 1 (R12 form): lane covers 16B (8 feats, q=l&31); wave halves process edges
//   e+half, e+2+half -> 4 chains in flight. __shfl_xor(32) reduce; lanes 0-31 combine
//   with X0, ds_write_b128 to swizzled LDS (byte(f) = f*2 ^ ((rl&7)<<4)).
// Phase 2: wave w computes cols [w*64,(w+1)*64) via 16x16x32 MFMA, K=256.
// Epilogue: v = relu((1-beta)*Hb + beta*acc + Xin).
//   LAST=0: store v (bf16) to Xout.
//   LAST=1: barrier (all phase-2 hs reads done) -> overwrite hs[hoff] in place with
//           bf16(v) (each slot owned by exactly one thread) -> barrier -> each wave
//           MFMAs its 32-col slice of lin1 (K=256, WT1) -> out = acc2 + l1b.
template <int LAST>
__global__ __launch_bounds__(256) void layer_kernel(
        const int* __restrict__ row_ptr, const int* __restrict__ s_src,
        const float* __restrict__ s_w, const u16* __restrict__ Xin,
        const u16* __restrict__ X0, u16* __restrict__ Xout,
        const u16* __restrict__ WT, float beta,
        const u16* __restrict__ WT1, const float* __restrict__ l1b,
        float* __restrict__ outp) {
    __shared__ __align__(16) u16 hs[16 * H_DIM];   // 8 KB, byte-swizzled
    const int w  = threadIdx.x >> 6;
    const int l  = threadIdx.x & 63;
    const int hi = l >> 4, lo = l & 15;
    const int half = l >> 5;          // 0|1: which edge of the pair
    const int q    = l & 31;          // 16B chunk index within the 512B row
    const int bm = blockIdx.x * 16;

    // ---- phase 1: gather 4 rows per wave, 4 edges in flight ----
    for (int i = 0; i < 4; ++i) {
        const int rl  = w * 4 + i;
        const int row = bm + rl;
        int beg = row_ptr[row], end = row_ptr[row + 1];
        if (beg < 0) beg = 0; if (end > E_EDGES) end = E_EDGES;   // defensive
        float accA[8] = {}, accB[8] = {};
        for (int e = beg; e < end; e += 4) {
            const int eA = e + half;
            const int eB = e + 2 + half;
            const int cA = (eA < end) ? eA : end - 1;   // end-1 >= beg >= 0 here
            const int cB = (eB < end) ? eB : end - 1;
            float wA = (eA < end) ? s_w[cA] : 0.f;
            float wB = (eB < end) ? s_w[cB] : 0.f;
            int sA = s_src[cA]; if (sA < 0) sA = 0; if (sA >= N_NODES) sA = N_NODES - 1;
            int sB = s_src[cB]; if (sB < 0) sB = 0; if (sB >= N_NODES) sB = N_NODES - 1;
            bf16x8 vA = *reinterpret_cast<const bf16x8*>(Xin + (long)sA * H_DIM + q * 8);
            bf16x8 vB = *reinterpret_cast<const bf16x8*>(Xin + (long)sB * H_DIM + q * 8);
            #pragma unroll
            for (int j = 0; j < 8; ++j) {
                accA[j] += wA * bf2f((u16)vA[j]);
                accB[j] += wB * bf2f((u16)vB[j]);
            }
        }
        float acc[8];
        #pragma unroll
        for (int j = 0; j < 8; ++j) {
            float s = accA[j] + accB[j];
            s += __shfl_xor(s, 32);
            acc[j] = s;
        }
        if (l < 32) {
            bf16x8 x0 = *reinterpret_cast<const bf16x8*>(X0 + (long)row * H_DIM + q * 8);
            bf16x8 ov;
            #pragma unroll
            for (int j = 0; j < 8; ++j)
                ov[j] = (short)f2bf(0.5f * acc[j] + 0.5f * bf2f((u16)x0[j]));
            const int off = rl * 512 + ((q * 16) ^ ((rl & 7) << 4));   // 16B-aligned
            *reinterpret_cast<bf16x8*>((char*)hs + off) = ov;
        }
    }
    __syncthreads();

    // ---- phase 2: conv GEMM on the LDS tile ----
    const int col0 = w * 64;
    f32x4 acc[4];
    #pragma unroll
    for (int t = 0; t < 4; ++t) acc[t] = (f32x4){0.f, 0.f, 0.f, 0.f};

    for (int k0 = 0; k0 < H_DIM; k0 += 32) {
        const int aoff = lo * 512 + (((k0 * 2) + hi * 16) ^ ((lo & 7) << 4));  // 16B-aligned
        bf16x8 a = *reinterpret_cast<const bf16x8*>((const char*)hs + aoff);
        #pragma unroll
        for (int t = 0; t < 4; ++t) {
            bf16x8 b = *reinterpret_cast<const bf16x8*>(
                    WT + (long)(col0 + t * 16 + lo) * H_DIM + k0 + hi * 8);
            acc[t] = __builtin_amdgcn_mfma_f32_16x16x32_bf16(a, b, acc[t], 0, 0, 0);
        }
    }

    if (LAST) __syncthreads();   // all phase-2 hs reads complete before in-place overwrite

    // ---- epilogue: residual + relu -> Xout (LAST: back into hs in place) ----
    #pragma unroll
    for (int t = 0; t < 4; ++t) {
        const int col = col0 + t * 16 + lo;
        #pragma unroll
        for (int r = 0; r < 4; ++r) {
            const int rl  = hi * 4 + r;
            const int row = bm + rl;
            const int hoff = rl * 512 + ((col * 2) ^ ((rl & 7) << 4));
            float hv = bf2f(*reinterpret_cast<const u16*>((const char*)hs + hoff));
            long idx = (long)row * H_DIM + col;
            float v = (1.f - beta) * hv + beta * acc[t][r] + bf2f(Xin[idx]);
            u16 vb = f2bf(fmaxf(v, 0.f));
            if (!LAST) {
                Xout[idx] = vb;
            } else {
                *reinterpret_cast<u16*>((char*)hs + hoff) = vb;   // slot owned by this thread
            }
        }
    }

    // ---- fused lin1 (last layer only): out = Xfinal @ WT1^T + l1b ----
    if (LAST) {
        __syncthreads();
        const int c1 = w * 32;
        f32x4 acc2[2];
        acc2[0] = (f32x4){0.f, 0.f, 0.f, 0.f};
        acc2[1] = (f32x4){0.f, 0.f, 0.f, 0.f};
        for (int k0 = 0; k0 < H_DIM; k0 += 32) {
            const int aoff = lo * 512 + (((k0 * 2) + hi * 16) ^ ((lo & 7) << 4));
            bf16x8 a = *reinterpret_cast<const bf16x8*>((const char*)hs + aoff);
            #pragma unroll
            for (int t = 0; t < 2; ++t) {
                bf16x8 b = *reinterpret_cast<const bf16x8*>(
                        WT1 + (long)(c1 + t * 16 + lo) * H_DIM + k0 + hi * 8);
                acc2[t] = __builtin_amdgcn_mfma_f32_16x16x32_bf16(a, b, acc2[t], 0, 0, 0);
            }
        }
        #pragma unroll
        for (int t = 0; t < 2; ++t) {
            const int col = c1 + t * 16 + lo;
            if (col < C_OUT) {
                const float bias = l1b[col];
                #pragma unroll
                for (int r = 0; r < 4; ++r) {
                    const int row = bm + hi * 4 + r;
                    outp[(long)row * C_OUT + col] = acc2[t][r] + bias;
                }
            }
        }
    }
}

// ---------------- MFMA GEMM (lin0 only): A fp32; X=X0=relu(acc+bias) ----------------
template <int K, int NT>
__global__ __launch_bounds__(256) void mfma_gemm_kernel(
        const float* __restrict__ Aptr, const u16* __restrict__ WT,
        const float* __restrict__ bias,
        u16* __restrict__ X, u16* __restrict__ X0) {
    const int w  = threadIdx.x >> 6;
    const int l  = threadIdx.x & 63;
    const int hi = l >> 4, lo = l & 15;
    const int bm = blockIdx.x * 16;
    const int col0 = w * (NT * 16);

    f32x4 acc[NT];
    #pragma unroll
    for (int t = 0; t < NT; ++t) acc[t] = (f32x4){0.f, 0.f, 0.f, 0.f};

    for (int k0 = 0; k0 < K; k0 += 32) {
        bf16x8 a;
        const float* ap = Aptr + (long)(bm + lo) * K + k0 + hi * 8;
        float4 f0 = *reinterpret_cast<const float4*>(ap);
        float4 f1 = *reinterpret_cast<const float4*>(ap + 4);
        a[0] = (short)f2bf(f0.x); a[1] = (short)f2bf(f0.y);
        a[2] = (short)f2bf(f0.z); a[3] = (short)f2bf(f0.w);
        a[4] = (short)f2bf(f1.x); a[5] = (short)f2bf(f1.y);
        a[6] = (short)f2bf(f1.z); a[7] = (short)f2bf(f1.w);
        #pragma unroll
        for (int t = 0; t < NT; ++t) {
            bf16x8 b = *reinterpret_cast<const bf16x8*>(
                    WT + (long)(col0 + t * 16 + lo) * K + k0 + hi * 8);
            acc[t] = __builtin_amdgcn_mfma_f32_16x16x32_bf16(a, b, acc[t], 0, 0, 0);
        }
    }

    #pragma unroll
    for (int t = 0; t < NT; ++t) {
        const int col = col0 + t * 16 + lo;
        #pragma unroll
        for (int r = 0; r < 4; ++r) {
            const int row = bm + hi * 4 + r;
            float v = fmaxf(acc[t][r] + bias[col], 0.f);
            u16 h = f2bf(v);
            long idx = (long)row * H_DIM + col;
            X[idx] = h; X0[idx] = h;
        }
    }
}

extern "C" void kernel_launch(void* const* d_in, const int* in_sizes, int n_in,
                              void* d_out, int out_size, void* d_ws, size_t ws_size,
                              hipStream_t stream) {
    const float* x_in = (const float*)d_in[0];
    const int*   esrc = (const int*)d_in[1];
    const int*   edst = (const int*)d_in[2];
    const float* ew   = (const float*)d_in[3];
    const float* l0w  = (const float*)d_in[4];
    const float* l0b  = (const float*)d_in[5];
    const float* cw   = (const float*)d_in[6];
    const float* l1w  = (const float*)d_in[7];
    const float* l1b  = (const float*)d_in[8];
    float* out = (float*)d_out;
    (void)in_sizes; (void)n_in; (void)out_size;

    char* ws = (char*)d_ws;
    auto al = [](size_t x) { return (x + 255) & ~(size_t)255; };
    size_t o = 0;
    const size_t NHb = (size_t)N_NODES * H_DIM * sizeof(u16);    // 25.6 MB
    u16* Xa = (u16*)(ws + o);  o += al(NHb);
    u16* Xb = (u16*)(ws + o);  o += al(NHb);
    u16* X0 = (u16*)(ws + o);  o += al(NHb);
    int* row_ptr = (int*)(ws + o); o += al((N_NODES + 1) * sizeof(int));
    int* cnt     = (int*)(ws + o); o += al((size_t)N_NODES * sizeof(int));
    int* s_src   = (int*)(ws + o); o += al((size_t)E_EDGES * sizeof(int));
    float* s_w   = (float*)(ws + o); o += al((size_t)E_EDGES * sizeof(float));
    u16* WT0 = (u16*)(ws + o); o += al((size_t)H_DIM * F_INDIM * sizeof(u16));          // 256 KB
    u16* WTc = (u16*)(ws + o); o += al((size_t)L_LAYERS * H_DIM * H_DIM * sizeof(u16)); // 512 KB
    u16* WT1 = (u16*)(ws + o); o += al((size_t)128 * H_DIM * sizeof(u16));              // 64 KB
    if (ws_size < o) return;   // diagnostic: clean zero-output => ws too small

    const int MBLK = N_NODES / 16;   // 3125, exact

    // 0. weight prep (single launch)
    prep_kernel<<<1664, 256, 0, stream>>>(l0w, cw, l1w, WT0, WTc, WT1);

    // 1. input projection: Xa = X0 = relu(x_in @ l0w + l0b)   [MFMA]
    mfma_gemm_kernel<F_INDIM, 4><<<MBLK, 256, 0, stream>>>(x_in, WT0, l0b, Xa, X0);

    // 2. CSR build (4 launches)
    zeroi_kernel<<<(N_NODES + 255) / 256, 256, 0, stream>>>(cnt, N_NODES);
    hist_kernel<<<(E_EDGES + 255) / 256, 256, 0, stream>>>(edst, cnt);
    scan_kernel<<<1, 256, 0, stream>>>(cnt, row_ptr);
    scatter_kernel<<<(E_EDGES + 255) / 256, 256, 0, stream>>>(esrc, edst, ew,
                                                              cnt, s_src, s_w);

    // 3. fused layers, ping-pong Xa <-> Xb; last layer fuses lin1 (in-place hs reuse)
    u16* Xcur = Xa;
    u16* Xnxt = Xb;
    for (int l = 0; l < L_LAYERS - 1; ++l) {
        float beta = logf(1.0f / (float)(l + 1) + 1.0f);
        layer_kernel<0><<<MBLK, 256, 0, stream>>>(
            row_ptr, s_src, s_w, Xcur, X0, Xnxt,
            WTc + (size_t)l * H_DIM * H_DIM, beta,
            nullptr, nullptr, nullptr);
        u16* tmp = Xcur; Xcur = Xnxt; Xnxt = tmp;
    }
    {
        const int l = L_LAYERS - 1;
        float beta = logf(1.0f / (float)(l + 1) + 1.0f);
        layer_kernel<1><<<MBLK, 256, 0, stream>>>(
            row_ptr, s_src, s_w, Xcur, X0, nullptr,
            WTc + (size_t)l * H_DIM * H_DIM, beta,
            WT1, l1b, out);
    }
}

// Round 18
// 1119.330 us; speedup vs baseline: 1.0569x; 1.0067x over previous
//
#include <hip/hip_runtime.h>
#include <math.h>

#define N_NODES 50000
#define E_EDGES 1600000
#define F_INDIM 512
#define H_DIM   256
#define C_OUT   121
#define L_LAYERS 4

typedef unsigned short u16;
typedef short bf16x8 __attribute__((ext_vector_type(8)));
typedef float f32x4  __attribute__((ext_vector_type(4)));

__device__ __forceinline__ float bf2f(u16 h) {
    return __uint_as_float(((unsigned int)h) << 16);
}
__device__ __forceinline__ u16 f2bf(float f) {
    unsigned int u = __float_as_uint(f);
    unsigned int r = u + 0x7FFFu + ((u >> 16) & 1u);   // round-to-nearest-even
    return (u16)(r >> 16);
}

// ---------------- utility ----------------
__global__ void zeroi_kernel(int* __restrict__ p, int n) {
    int i = blockIdx.x * blockDim.x + threadIdx.x;
    if (i < n) p[i] = 0;
}

// single prep kernel: all weight transposes+bf16 conversion in one launch
__global__ void prep_kernel(const float* __restrict__ l0w, const float* __restrict__ cw,
                            const float* __restrict__ l1w, u16* __restrict__ WT0,
                            u16* __restrict__ WTc, u16* __restrict__ WT1) {
    int i = blockIdx.x * blockDim.x + threadIdx.x;
    if (i < 131072) {                       // 256*512
        int n = i >> 9, k = i & 511;
        WT0[i] = f2bf(l0w[(long)k * H_DIM + n]);
        return;
    }
    i -= 131072;
    if (i < 262144) {                       // 4*256*256
        int l = i >> 16, j = i & 65535, n = j >> 8, k = j & 255;
        WTc[(l << 16) + j] = f2bf(cw[(long)l * 65536 + (long)k * H_DIM + n]);
        return;
    }
    i -= 262144;
    if (i < 32768) {                        // 128*256
        int n = i >> 8, k = i & 255;
        WT1[i] = (n < C_OUT) ? f2bf(l1w[(long)k * C_OUT + n]) : (u16)0;
    }
}

// ---------------- CSR build ----------------
__global__ void hist_kernel(const int* __restrict__ dst, int* __restrict__ deg) {
    int e = blockIdx.x * blockDim.x + threadIdx.x;
    if (e < E_EDGES) {
        int d = dst[e];
        if (d >= 0 && d < N_NODES) atomicAdd(&deg[d], 1);
    }
}

// single block, 256 threads: exclusive scan; writes row_ptr AND seeds cnt with the
// row base so scatter's atomicAdd returns an absolute slot
__global__ void scan_kernel(int* cnt, int* __restrict__ row_ptr) {
    __shared__ int sums[256];
    const int t = threadIdx.x;
    const int CH = (N_NODES + 255) / 256;   // 196
    const int base = t * CH;
    int s = 0;
    for (int i = 0; i < CH; ++i) {
        int idx = base + i;
        if (idx < N_NODES) s += cnt[idx];
    }
    sums[t] = s;
    __syncthreads();
    for (int off = 1; off < 256; off <<= 1) {
        int v = (t >= off) ? sums[t - off] : 0;
        __syncthreads();
        sums[t] += v;
        __syncthreads();
    }
    int run = (t == 0) ? 0 : sums[t - 1];
    for (int i = 0; i < CH; ++i) {
        int idx = base + i;
        if (idx < N_NODES) {
            int dv = cnt[idx];
            row_ptr[idx] = run;
            cnt[idx] = run;     // seed for scatter
            run += dv;
        }
    }
    if (t == 255) row_ptr[N_NODES] = run;    // == E
}

__global__ void scatter_kernel(const int* __restrict__ src, const int* __restrict__ dst,
                               const float* __restrict__ w,
                               int* __restrict__ cnt, int* __restrict__ s_src,
                               float* __restrict__ s_w) {
    int e = blockIdx.x * blockDim.x + threadIdx.x;
    if (e < E_EDGES) {
        int d = dst[e];
        if (d < 0) d = 0; if (d >= N_NODES) d = N_NODES - 1;   // defensive
        long idx = atomicAdd(&cnt[d], 1);                      // absolute slot
        if (idx < 0) idx = 0; if (idx >= E_EDGES) idx = E_EDGES - 1;  // defensive
        s_src[idx] = src[e];
        s_w[idx]   = w[e];
    }
}

// ===== fused layer: gather(A@Xin) + combine -> LDS tile -> MFMA conv -> residual =====
// R18: block = 16 dst rows, 8 WAVES (512 threads), 2 rows/wave — halves each wave's
//   serial gather chain (~64 edges vs ~128) at identical per-thread register state;
//   total resident waves unchanged (thread-limited). R14 showed deeper per-wave ILP
//   regresses via VGPR/occupancy; this attacks the chain on the wave axis instead.
// Phase 1 (R12 inner loop): lane covers 16B (8 feats, q=l&31); wave halves process
//   edges e+half, e+2+half -> 4 chains in flight. __shfl_xor(32) reduce; lanes 0-31
//   combine with X0, ds_write_b128 to swizzled LDS (byte(f) = f*2 ^ ((rl&7)<<4)).
// Phase 2: wave w computes cols [w*32,(w+1)*32) via 16x16x32 MFMA, K=256.
// Epilogue: v = relu((1-beta)*Hb + beta*acc + Xin).
//   LAST=0: store v (bf16) to Xout.
//   LAST=1: barrier -> overwrite hs[hoff] in place (slot owned by one thread) ->
//           barrier -> each wave MFMAs its 16-col slice of lin1 -> out = acc2 + l1b.
template <int LAST>
__global__ __launch_bounds__(512) void layer_kernel(
        const int* __restrict__ row_ptr, const int* __restrict__ s_src,
        const float* __restrict__ s_w, const u16* __restrict__ Xin,
        const u16* __restrict__ X0, u16* __restrict__ Xout,
        const u16* __restrict__ WT, float beta,
        const u16* __restrict__ WT1, const float* __restrict__ l1b,
        float* __restrict__ outp) {
    __shared__ __align__(16) u16 hs[16 * H_DIM];   // 8 KB, byte-swizzled
    const int w  = threadIdx.x >> 6;   // 0..7
    const int l  = threadIdx.x & 63;
    const int hi = l >> 4, lo = l & 15;
    const int half = l >> 5;          // 0|1: which edge of the pair
    const int q    = l & 31;          // 16B chunk index within the 512B row
    const int bm = blockIdx.x * 16;

    // ---- phase 1: gather 2 rows per wave, 4 edges in flight ----
    for (int i = 0; i < 2; ++i) {
        const int rl  = w * 2 + i;
        const int row = bm + rl;
        int beg = row_ptr[row], end = row_ptr[row + 1];
        if (beg < 0) beg = 0; if (end > E_EDGES) end = E_EDGES;   // defensive
        float accA[8] = {}, accB[8] = {};
        for (int e = beg; e < end; e += 4) {
            const int eA = e + half;
            const int eB = e + 2 + half;
            const int cA = (eA < end) ? eA : end - 1;   // end-1 >= beg >= 0 here
            const int cB = (eB < end) ? eB : end - 1;
            float wA = (eA < end) ? s_w[cA] : 0.f;
            float wB = (eB < end) ? s_w[cB] : 0.f;
            int sA = s_src[cA]; if (sA < 0) sA = 0; if (sA >= N_NODES) sA = N_NODES - 1;
            int sB = s_src[cB]; if (sB < 0) sB = 0; if (sB >= N_NODES) sB = N_NODES - 1;
            bf16x8 vA = *reinterpret_cast<const bf16x8*>(Xin + (long)sA * H_DIM + q * 8);
            bf16x8 vB = *reinterpret_cast<const bf16x8*>(Xin + (long)sB * H_DIM + q * 8);
            #pragma unroll
            for (int j = 0; j < 8; ++j) {
                accA[j] += wA * bf2f((u16)vA[j]);
                accB[j] += wB * bf2f((u16)vB[j]);
            }
        }
        float acc[8];
        #pragma unroll
        for (int j = 0; j < 8; ++j) {
            float s = accA[j] + accB[j];
            s += __shfl_xor(s, 32);
            acc[j] = s;
        }
        if (l < 32) {
            bf16x8 x0 = *reinterpret_cast<const bf16x8*>(X0 + (long)row * H_DIM + q * 8);
            bf16x8 ov;
            #pragma unroll
            for (int j = 0; j < 8; ++j)
                ov[j] = (short)f2bf(0.5f * acc[j] + 0.5f * bf2f((u16)x0[j]));
            const int off = rl * 512 + ((q * 16) ^ ((rl & 7) << 4));   // 16B-aligned
            *reinterpret_cast<bf16x8*>((char*)hs + off) = ov;
        }
    }
    __syncthreads();

    // ---- phase 2: conv GEMM on the LDS tile (8 waves x 32 cols) ----
    const int col0 = w * 32;
    f32x4 acc[2];
    acc[0] = (f32x4){0.f, 0.f, 0.f, 0.f};
    acc[1] = (f32x4){0.f, 0.f, 0.f, 0.f};

    for (int k0 = 0; k0 < H_DIM; k0 += 32) {
        const int aoff = lo * 512 + (((k0 * 2) + hi * 16) ^ ((lo & 7) << 4));  // 16B-aligned
        bf16x8 a = *reinterpret_cast<const bf16x8*>((const char*)hs + aoff);
        #pragma unroll
        for (int t = 0; t < 2; ++t) {
            bf16x8 b = *reinterpret_cast<const bf16x8*>(
                    WT + (long)(col0 + t * 16 + lo) * H_DIM + k0 + hi * 8);
            acc[t] = __builtin_amdgcn_mfma_f32_16x16x32_bf16(a, b, acc[t], 0, 0, 0);
        }
    }

    if (LAST) __syncthreads();   // all phase-2 hs reads complete before in-place overwrite

    // ---- epilogue: residual + relu -> Xout (LAST: back into hs in place) ----
    #pragma unroll
    for (int t = 0; t < 2; ++t) {
        const int col = col0 + t * 16 + lo;
        #pragma unroll
        for (int r = 0; r < 4; ++r) {
            const int rl  = hi * 4 + r;
            const int row = bm + rl;
            const int hoff = rl * 512 + ((col * 2) ^ ((rl & 7) << 4));
            float hv = bf2f(*reinterpret_cast<const u16*>((const char*)hs + hoff));
            long idx = (long)row * H_DIM + col;
            float v = (1.f - beta) * hv + beta * acc[t][r] + bf2f(Xin[idx]);
            u16 vb = f2bf(fmaxf(v, 0.f));
            if (!LAST) {
                Xout[idx] = vb;
            } else {
                *reinterpret_cast<u16*>((char*)hs + hoff) = vb;   // slot owned by this thread
            }
        }
    }

    // ---- fused lin1 (last layer only): out = Xfinal @ WT1^T + l1b ----
    if (LAST) {
        __syncthreads();
        const int c1 = w * 16;
        f32x4 acc2 = (f32x4){0.f, 0.f, 0.f, 0.f};
        for (int k0 = 0; k0 < H_DIM; k0 += 32) {
            const int aoff = lo * 512 + (((k0 * 2) + hi * 16) ^ ((lo & 7) << 4));
            bf16x8 a = *reinterpret_cast<const bf16x8*>((const char*)hs + aoff);
            bf16x8 b = *reinterpret_cast<const bf16x8*>(
                    WT1 + (long)(c1 + lo) * H_DIM + k0 + hi * 8);
            acc2 = __builtin_amdgcn_mfma_f32_16x16x32_bf16(a, b, acc2, 0, 0, 0);
        }
        const int col = c1 + lo;
        if (col < C_OUT) {
            const float bias = l1b[col];
            #pragma unroll
            for (int r = 0; r < 4; ++r) {
                const int row = bm + hi * 4 + r;
                outp[(long)row * C_OUT + col] = acc2[r] + bias;
            }
        }
    }
}

// ---------------- MFMA GEMM (lin0 only): A fp32; X=X0=relu(acc+bias) ----------------
template <int K, int NT>
__global__ __launch_bounds__(256) void mfma_gemm_kernel(
        const float* __restrict__ Aptr, const u16* __restrict__ WT,
        const float* __restrict__ bias,
        u16* __restrict__ X, u16* __restrict__ X0) {
    const int w  = threadIdx.x >> 6;
    const int l  = threadIdx.x & 63;
    const int hi = l >> 4, lo = l & 15;
    const int bm = blockIdx.x * 16;
    const int col0 = w * (NT * 16);

    f32x4 acc[NT];
    #pragma unroll
    for (int t = 0; t < NT; ++t) acc[t] = (f32x4){0.f, 0.f, 0.f, 0.f};

    for (int k0 = 0; k0 < K; k0 += 32) {
        bf16x8 a;
        const float* ap = Aptr + (long)(bm + lo) * K + k0 + hi * 8;
        float4 f0 = *reinterpret_cast<const float4*>(ap);
        float4 f1 = *reinterpret_cast<const float4*>(ap + 4);
        a[0] = (short)f2bf(f0.x); a[1] = (short)f2bf(f0.y);
        a[2] = (short)f2bf(f0.z); a[3] = (short)f2bf(f0.w);
        a[4] = (short)f2bf(f1.x); a[5] = (short)f2bf(f1.y);
        a[6] = (short)f2bf(f1.z); a[7] = (short)f2bf(f1.w);
        #pragma unroll
        for (int t = 0; t < NT; ++t) {
            bf16x8 b = *reinterpret_cast<const bf16x8*>(
                    WT + (long)(col0 + t * 16 + lo) * K + k0 + hi * 8);
            acc[t] = __builtin_amdgcn_mfma_f32_16x16x32_bf16(a, b, acc[t], 0, 0, 0);
        }
    }

    #pragma unroll
    for (int t = 0; t < NT; ++t) {
        const int col = col0 + t * 16 + lo;
        #pragma unroll
        for (int r = 0; r < 4; ++r) {
            const int row = bm + hi * 4 + r;
            float v = fmaxf(acc[t][r] + bias[col], 0.f);
            u16 h = f2bf(v);
            long idx = (long)row * H_DIM + col;
            X[idx] = h; X0[idx] = h;
        }
    }
}

extern "C" void kernel_launch(void* const* d_in, const int* in_sizes, int n_in,
                              void* d_out, int out_size, void* d_ws, size_t ws_size,
                              hipStream_t stream) {
    const float* x_in = (const float*)d_in[0];
    const int*   esrc = (const int*)d_in[1];
    const int*   edst = (const int*)d_in[2];
    const float* ew   = (const float*)d_in[3];
    const float* l0w  = (const float*)d_in[4];
    const float* l0b  = (const float*)d_in[5];
    const float* cw   = (const float*)d_in[6];
    const float* l1w  = (const float*)d_in[7];
    const float* l1b  = (const float*)d_in[8];
    float* out = (float*)d_out;
    (void)in_sizes; (void)n_in; (void)out_size;

    char* ws = (char*)d_ws;
    auto al = [](size_t x) { return (x + 255) & ~(size_t)255; };
    size_t o = 0;
    const size_t NHb = (size_t)N_NODES * H_DIM * sizeof(u16);    // 25.6 MB
    u16* Xa = (u16*)(ws + o);  o += al(NHb);
    u16* Xb = (u16*)(ws + o);  o += al(NHb);
    u16* X0 = (u16*)(ws + o);  o += al(NHb);
    int* row_ptr = (int*)(ws + o); o += al((N_NODES + 1) * sizeof(int));
    int* cnt     = (int*)(ws + o); o += al((size_t)N_NODES * sizeof(int));
    int* s_src   = (int*)(ws + o); o += al((size_t)E_EDGES * sizeof(int));
    float* s_w   = (float*)(ws + o); o += al((size_t)E_EDGES * sizeof(float));
    u16* WT0 = (u16*)(ws + o); o += al((size_t)H_DIM * F_INDIM * sizeof(u16));          // 256 KB
    u16* WTc = (u16*)(ws + o); o += al((size_t)L_LAYERS * H_DIM * H_DIM * sizeof(u16)); // 512 KB
    u16* WT1 = (u16*)(ws + o); o += al((size_t)128 * H_DIM * sizeof(u16));              // 64 KB
    if (ws_size < o) return;   // diagnostic: clean zero-output => ws too small

    const int MBLK = N_NODES / 16;   // 3125, exact

    // 0. weight prep (single launch)
    prep_kernel<<<1664, 256, 0, stream>>>(l0w, cw, l1w, WT0, WTc, WT1);

    // 1. input projection: Xa = X0 = relu(x_in @ l0w + l0b)   [MFMA]
    mfma_gemm_kernel<F_INDIM, 4><<<MBLK, 256, 0, stream>>>(x_in, WT0, l0b, Xa, X0);

    // 2. CSR build (4 launches)
    zeroi_kernel<<<(N_NODES + 255) / 256, 256, 0, stream>>>(cnt, N_NODES);
    hist_kernel<<<(E_EDGES + 255) / 256, 256, 0, stream>>>(edst, cnt);
    scan_kernel<<<1, 256, 0, stream>>>(cnt, row_ptr);
    scatter_kernel<<<(E_EDGES + 255) / 256, 256, 0, stream>>>(esrc, edst, ew,
                                                              cnt, s_src, s_w);

    // 3. fused layers, ping-pong Xa <-> Xb; last layer fuses lin1 (in-place hs reuse)
    u16* Xcur = Xa;
    u16* Xnxt = Xb;
    for (int l = 0; l < L_LAYERS - 1; ++l) {
        float beta = logf(1.0f / (float)(l + 1) + 1.0f);
        layer_kernel<0><<<MBLK, 512, 0, stream>>>(
            row_ptr, s_src, s_w, Xcur, X0, Xnxt,
            WTc + (size_t)l * H_DIM * H_DIM, beta,
            nullptr, nullptr, nullptr);
        u16* tmp = Xcur; Xcur = Xnxt; Xnxt = tmp;
    }
    {
        const int l = L_LAYERS - 1;
        float beta = logf(1.0f / (float)(l + 1) + 1.0f);
        layer_kernel<1><<<MBLK, 512, 0, stream>>>(
            row_ptr, s_src, s_w, Xcur, X0, nullptr,
            WTc + (size_t)l * H_DIM * H_DIM, beta,
            WT1, l1b, out);
    }
}

// Round 20
// 1096.118 us; speedup vs baseline: 1.0793x; 1.0212x over previous
//
#include <hip/hip_runtime.h>
#include <math.h>

#define N_NODES 50000
#define E_EDGES 1600000
#define F_INDIM 512
#define H_DIM   256
#define C_OUT   121
#define L_LAYERS 4

typedef unsigned short u16;
typedef short bf16x8 __attribute__((ext_vector_type(8)));
typedef float f32x4  __attribute__((ext_vector_type(4)));

__device__ __forceinline__ float bf2f(u16 h) {
    return __uint_as_float(((unsigned int)h) << 16);
}
__device__ __forceinline__ u16 f2bf(float f) {
    unsigned int u = __float_as_uint(f);
    unsigned int r = u + 0x7FFFu + ((u >> 16) & 1u);   // round-to-nearest-even
    return (u16)(r >> 16);
}

// single prep kernel: all weight transposes+bf16 conversion + cnt zeroing, one launch
__global__ void prep_kernel(const float* __restrict__ l0w, const float* __restrict__ cw,
                            const float* __restrict__ l1w, u16* __restrict__ WT0,
                            u16* __restrict__ WTc, u16* __restrict__ WT1,
                            int* __restrict__ cnt) {
    int i = blockIdx.x * blockDim.x + threadIdx.x;
    if (i < 131072) {                       // 256*512
        int n = i >> 9, k = i & 511;
        WT0[i] = f2bf(l0w[(long)k * H_DIM + n]);
        return;
    }
    i -= 131072;
    if (i < 262144) {                       // 4*256*256
        int l = i >> 16, j = i & 65535, n = j >> 8, k = j & 255;
        WTc[(l << 16) + j] = f2bf(cw[(long)l * 65536 + (long)k * H_DIM + n]);
        return;
    }
    i -= 262144;
    if (i < 32768) {                        // 128*256
        int n = i >> 8, k = i & 255;
        WT1[i] = (n < C_OUT) ? f2bf(l1w[(long)k * C_OUT + n]) : (u16)0;
        return;
    }
    i -= 32768;
    if (i < N_NODES) cnt[i] = 0;            // CSR degree counter zeroing
}

// ---------------- CSR build ----------------
// 4 edges per thread via int4 (E_EDGES % 4 == 0)
__global__ void hist_kernel(const int* __restrict__ dst, int* __restrict__ deg) {
    int i = blockIdx.x * blockDim.x + threadIdx.x;
    if (i < E_EDGES / 4) {
        int4 d4 = reinterpret_cast<const int4*>(dst)[i];
        if (d4.x >= 0 && d4.x < N_NODES) atomicAdd(&deg[d4.x], 1);
        if (d4.y >= 0 && d4.y < N_NODES) atomicAdd(&deg[d4.y], 1);
        if (d4.z >= 0 && d4.z < N_NODES) atomicAdd(&deg[d4.z], 1);
        if (d4.w >= 0 && d4.w < N_NODES) atomicAdd(&deg[d4.w], 1);
    }
}

// single block, 1024 threads: exclusive scan; writes row_ptr AND seeds cnt with the
// row base so scatter's atomicAdd returns an absolute slot
__global__ void scan_kernel(int* cnt, int* __restrict__ row_ptr) {
    __shared__ int sums[1024];
    const int t = threadIdx.x;
    const int CH = (N_NODES + 1023) / 1024;   // 49
    const int base = t * CH;
    int s = 0;
    for (int i = 0; i < CH; ++i) {
        int idx = base + i;
        if (idx < N_NODES) s += cnt[idx];
    }
    sums[t] = s;
    __syncthreads();
    for (int off = 1; off < 1024; off <<= 1) {
        int v = (t >= off) ? sums[t - off] : 0;
        __syncthreads();
        sums[t] += v;
        __syncthreads();
    }
    int run = (t == 0) ? 0 : sums[t - 1];
    for (int i = 0; i < CH; ++i) {
        int idx = base + i;
        if (idx < N_NODES) {
            int dv = cnt[idx];
            row_ptr[idx] = run;
            cnt[idx] = run;     // seed for scatter
            run += dv;
        }
    }
    if (t == 1023) row_ptr[N_NODES] = run;    // == E
}

// 4 edges per thread via int4/float4
__global__ void scatter_kernel(const int* __restrict__ src, const int* __restrict__ dst,
                               const float* __restrict__ w,
                               int* __restrict__ cnt, int* __restrict__ s_src,
                               float* __restrict__ s_w) {
    int i = blockIdx.x * blockDim.x + threadIdx.x;
    if (i < E_EDGES / 4) {
        int4   s4 = reinterpret_cast<const int4*>(src)[i];
        int4   d4 = reinterpret_cast<const int4*>(dst)[i];
        float4 w4 = reinterpret_cast<const float4*>(w)[i];
        int   sv[4] = {s4.x, s4.y, s4.z, s4.w};
        int   dv[4] = {d4.x, d4.y, d4.z, d4.w};
        float wv[4] = {w4.x, w4.y, w4.z, w4.w};
        #pragma unroll
        for (int u = 0; u < 4; ++u) {
            int d = dv[u];
            if (d < 0) d = 0; if (d >= N_NODES) d = N_NODES - 1;   // defensive
            long idx = atomicAdd(&cnt[d], 1);                      // absolute slot
            if (idx < 0) idx = 0; if (idx >= E_EDGES) idx = E_EDGES - 1;  // defensive
            s_src[idx] = sv[u];
            s_w[idx]   = wv[u];
        }
    }
}

// ===== fused layer: gather(A@Xin) + combine -> LDS tile -> MFMA conv -> residual =====
// (byte-identical to R18: 16 rows, 8 waves/512 threads, 2 rows/wave, 8KB LDS)
template <int LAST>
__global__ __launch_bounds__(512) void layer_kernel(
        const int* __restrict__ row_ptr, const int* __restrict__ s_src,
        const float* __restrict__ s_w, const u16* __restrict__ Xin,
        const u16* __restrict__ X0, u16* __restrict__ Xout,
        const u16* __restrict__ WT, float beta,
        const u16* __restrict__ WT1, const float* __restrict__ l1b,
        float* __restrict__ outp) {
    __shared__ __align__(16) u16 hs[16 * H_DIM];   // 8 KB, byte-swizzled
    const int w  = threadIdx.x >> 6;   // 0..7
    const int l  = threadIdx.x & 63;
    const int hi = l >> 4, lo = l & 15;
    const int half = l >> 5;          // 0|1: which edge of the pair
    const int q    = l & 31;          // 16B chunk index within the 512B row
    const int bm = blockIdx.x * 16;

    // ---- phase 1: gather 2 rows per wave, 4 edges in flight ----
    for (int i = 0; i < 2; ++i) {
        const int rl  = w * 2 + i;
        const int row = bm + rl;
        int beg = row_ptr[row], end = row_ptr[row + 1];
        if (beg < 0) beg = 0; if (end > E_EDGES) end = E_EDGES;   // defensive
        float accA[8] = {}, accB[8] = {};
        for (int e = beg; e < end; e += 4) {
            const int eA = e + half;
            const int eB = e + 2 + half;
            const int cA = (eA < end) ? eA : end - 1;   // end-1 >= beg >= 0 here
            const int cB = (eB < end) ? eB : end - 1;
            float wA = (eA < end) ? s_w[cA] : 0.f;
            float wB = (eB < end) ? s_w[cB] : 0.f;
            int sA = s_src[cA]; if (sA < 0) sA = 0; if (sA >= N_NODES) sA = N_NODES - 1;
            int sB = s_src[cB]; if (sB < 0) sB = 0; if (sB >= N_NODES) sB = N_NODES - 1;
            bf16x8 vA = *reinterpret_cast<const bf16x8*>(Xin + (long)sA * H_DIM + q * 8);
            bf16x8 vB = *reinterpret_cast<const bf16x8*>(Xin + (long)sB * H_DIM + q * 8);
            #pragma unroll
            for (int j = 0; j < 8; ++j) {
                accA[j] += wA * bf2f((u16)vA[j]);
                accB[j] += wB * bf2f((u16)vB[j]);
            }
        }
        float acc[8];
        #pragma unroll
        for (int j = 0; j < 8; ++j) {
            float s = accA[j] + accB[j];
            s += __shfl_xor(s, 32);
            acc[j] = s;
        }
        if (l < 32) {
            bf16x8 x0 = *reinterpret_cast<const bf16x8*>(X0 + (long)row * H_DIM + q * 8);
            bf16x8 ov;
            #pragma unroll
            for (int j = 0; j < 8; ++j)
                ov[j] = (short)f2bf(0.5f * acc[j] + 0.5f * bf2f((u16)x0[j]));
            const int off = rl * 512 + ((q * 16) ^ ((rl & 7) << 4));   // 16B-aligned
            *reinterpret_cast<bf16x8*>((char*)hs + off) = ov;
        }
    }
    __syncthreads();

    // ---- phase 2: conv GEMM on the LDS tile (8 waves x 32 cols) ----
    const int col0 = w * 32;
    f32x4 acc[2];
    acc[0] = (f32x4){0.f, 0.f, 0.f, 0.f};
    acc[1] = (f32x4){0.f, 0.f, 0.f, 0.f};

    for (int k0 = 0; k0 < H_DIM; k0 += 32) {
        const int aoff = lo * 512 + (((k0 * 2) + hi * 16) ^ ((lo & 7) << 4));  // 16B-aligned
        bf16x8 a = *reinterpret_cast<const bf16x8*>((const char*)hs + aoff);
        #pragma unroll
        for (int t = 0; t < 2; ++t) {
            bf16x8 b = *reinterpret_cast<const bf16x8*>(
                    WT + (long)(col0 + t * 16 + lo) * H_DIM + k0 + hi * 8);
            acc[t] = __builtin_amdgcn_mfma_f32_16x16x32_bf16(a, b, acc[t], 0, 0, 0);
        }
    }

    if (LAST) __syncthreads();   // all phase-2 hs reads complete before in-place overwrite

    // ---- epilogue: residual + relu -> Xout (LAST: back into hs in place) ----
    #pragma unroll
    for (int t = 0; t < 2; ++t) {
        const int col = col0 + t * 16 + lo;
        #pragma unroll
        for (int r = 0; r < 4; ++r) {
            const int rl  = hi * 4 + r;
            const int row = bm + rl;
            const int hoff = rl * 512 + ((col * 2) ^ ((rl & 7) << 4));
            float hv = bf2f(*reinterpret_cast<const u16*>((const char*)hs + hoff));
            long idx = (long)row * H_DIM + col;
            float v = (1.f - beta) * hv + beta * acc[t][r] + bf2f(Xin[idx]);
            u16 vb = f2bf(fmaxf(v, 0.f));
            if (!LAST) {
                Xout[idx] = vb;
            } else {
                *reinterpret_cast<u16*>((char*)hs + hoff) = vb;   // slot owned by this thread
            }
        }
    }

    // ---- fused lin1 (last layer only): out = Xfinal @ WT1^T + l1b ----
    if (LAST) {
        __syncthreads();
        const int c1 = w * 16;
        f32x4 acc2 = (f32x4){0.f, 0.f, 0.f, 0.f};
        for (int k0 = 0; k0 < H_DIM; k0 += 32) {
            const int aoff = lo * 512 + (((k0 * 2) + hi * 16) ^ ((lo & 7) << 4));
            bf16x8 a = *reinterpret_cast<const bf16x8*>((const char*)hs + aoff);
            bf16x8 b = *reinterpret_cast<const bf16x8*>(
                    WT1 + (long)(c1 + lo) * H_DIM + k0 + hi * 8);
            acc2 = __builtin_amdgcn_mfma_f32_16x16x32_bf16(a, b, acc2, 0, 0, 0);
        }
        const int col = c1 + lo;
        if (col < C_OUT) {
            const float bias = l1b[col];
            #pragma unroll
            for (int r = 0; r < 4; ++r) {
                const int row = bm + hi * 4 + r;
                outp[(long)row * C_OUT + col] = acc2[r] + bias;
            }
        }
    }
}

// ---------------- MFMA GEMM (lin0 only): A fp32; X=X0=relu(acc+bias) ----------------
template <int K, int NT>
__global__ __launch_bounds__(256) void mfma_gemm_kernel(
        const float* __restrict__ Aptr, const u16* __restrict__ WT,
        const float* __restrict__ bias,
        u16* __restrict__ X, u16* __restrict__ X0) {
    const int w  = threadIdx.x >> 6;
    const int l  = threadIdx.x & 63;
    const int hi = l >> 4, lo = l & 15;
    const int bm = blockIdx.x * 16;
    const int col0 = w * (NT * 16);

    f32x4 acc[NT];
    #pragma unroll
    for (int t = 0; t < NT; ++t) acc[t] = (f32x4){0.f, 0.f, 0.f, 0.f};

    for (int k0 = 0; k0 < K; k0 += 32) {
        bf16x8 a;
        const float* ap = Aptr + (long)(bm + lo) * K + k0 + hi * 8;
        float4 f0 = *reinterpret_cast<const float4*>(ap);
        float4 f1 = *reinterpret_cast<const float4*>(ap + 4);
        a[0] = (short)f2bf(f0.x); a[1] = (short)f2bf(f0.y);
        a[2] = (short)f2bf(f0.z); a[3] = (short)f2bf(f0.w);
        a[4] = (short)f2bf(f1.x); a[5] = (short)f2bf(f1.y);
        a[6] = (short)f2bf(f1.z); a[7] = (short)f2bf(f1.w);
        #pragma unroll
        for (int t = 0; t < NT; ++t) {
            bf16x8 b = *reinterpret_cast<const bf16x8*>(
                    WT + (long)(col0 + t * 16 + lo) * K + k0 + hi * 8);
            acc[t] = __builtin_amdgcn_mfma_f32_16x16x32_bf16(a, b, acc[t], 0, 0, 0);
        }
    }

    #pragma unroll
    for (int t = 0; t < NT; ++t) {
        const int col = col0 + t * 16 + lo;
        #pragma unroll
        for (int r = 0; r < 4; ++r) {
            const int row = bm + hi * 4 + r;
            float v = fmaxf(acc[t][r] + bias[col], 0.f);
            u16 h = f2bf(v);
            long idx = (long)row * H_DIM + col;
            X[idx] = h; X0[idx] = h;
        }
    }
}

extern "C" void kernel_launch(void* const* d_in, const int* in_sizes, int n_in,
                              void* d_out, int out_size, void* d_ws, size_t ws_size,
                              hipStream_t stream) {
    const float* x_in = (const float*)d_in[0];
    const int*   esrc = (const int*)d_in[1];
    const int*   edst = (const int*)d_in[2];
    const float* ew   = (const float*)d_in[3];
    const float* l0w  = (const float*)d_in[4];
    const float* l0b  = (const float*)d_in[5];
    const float* cw   = (const float*)d_in[6];
    const float* l1w  = (const float*)d_in[7];
    const float* l1b  = (const float*)d_in[8];
    float* out = (float*)d_out;
    (void)in_sizes; (void)n_in; (void)out_size;

    char* ws = (char*)d_ws;
    auto al = [](size_t x) { return (x + 255) & ~(size_t)255; };
    size_t o = 0;
    const size_t NHb = (size_t)N_NODES * H_DIM * sizeof(u16);    // 25.6 MB
    u16* Xa = (u16*)(ws + o);  o += al(NHb);
    u16* Xb = (u16*)(ws + o);  o += al(NHb);
    u16* X0 = (u16*)(ws + o);  o += al(NHb);
    int* row_ptr = (int*)(ws + o); o += al((N_NODES + 1) * sizeof(int));
    int* cnt     = (int*)(ws + o); o += al((size_t)N_NODES * sizeof(int));
    int* s_src   = (int*)(ws + o); o += al((size_t)E_EDGES * sizeof(int));
    float* s_w   = (float*)(ws + o); o += al((size_t)E_EDGES * sizeof(float));
    u16* WT0 = (u16*)(ws + o); o += al((size_t)H_DIM * F_INDIM * sizeof(u16));          // 256 KB
    u16* WTc = (u16*)(ws + o); o += al((size_t)L_LAYERS * H_DIM * H_DIM * sizeof(u16)); // 512 KB
    u16* WT1 = (u16*)(ws + o); o += al((size_t)128 * H_DIM * sizeof(u16));              // 64 KB
    if (ws_size < o) return;   // diagnostic: clean zero-output => ws too small

    const int MBLK = N_NODES / 16;   // 3125, exact

    // 0. weight prep + cnt zeroing (single launch: 425984+50000 elems -> 1860 blocks)
    prep_kernel<<<1860, 256, 0, stream>>>(l0w, cw, l1w, WT0, WTc, WT1, cnt);

    // 1. input projection: Xa = X0 = relu(x_in @ l0w + l0b)   [MFMA]
    mfma_gemm_kernel<F_INDIM, 4><<<MBLK, 256, 0, stream>>>(x_in, WT0, l0b, Xa, X0);

    // 2. CSR build (3 launches: hist x4, scan-1024, scatter x4)
    hist_kernel<<<(E_EDGES / 4 + 255) / 256, 256, 0, stream>>>(edst, cnt);
    scan_kernel<<<1, 1024, 0, stream>>>(cnt, row_ptr);
    scatter_kernel<<<(E_EDGES / 4 + 255) / 256, 256, 0, stream>>>(esrc, edst, ew,
                                                                  cnt, s_src, s_w);

    // 3. fused layers, ping-pong Xa <-> Xb; last layer fuses lin1 (in-place hs reuse)
    u16* Xcur = Xa;
    u16* Xnxt = Xb;
    for (int l = 0; l < L_LAYERS - 1; ++l) {
        float beta = logf(1.0f / (float)(l + 1) + 1.0f);
        layer_kernel<0><<<MBLK, 512, 0, stream>>>(
            row_ptr, s_src, s_w, Xcur, X0, Xnxt,
            WTc + (size_t)l * H_DIM * H_DIM, beta,
            nullptr, nullptr, nullptr);
        u16* tmp = Xcur; Xcur = Xnxt; Xnxt = tmp;
    }
    {
        const int l = L_LAYERS - 1;
        float beta = logf(1.0f / (float)(l + 1) + 1.0f);
        layer_kernel<1><<<MBLK, 512, 0, stream>>>(
            row_ptr, s_src, s_w, Xcur, X0, nullptr,
            WTc + (size_t)l * H_DIM * H_DIM, beta,
            WT1, l1b, out);
    }
}

// Round 21
// 1064.537 us; speedup vs baseline: 1.1113x; 1.0297x over previous
//
#include <hip/hip_runtime.h>
#include <math.h>

#define N_NODES 50000
#define E_EDGES 1600000
#define F_INDIM 512
#define H_DIM   256
#define C_OUT   121
#define L_LAYERS 4
#define MCAP    1280   // per-block edge-meta LDS capacity (mean span 512, ~5 sigma ~630)

typedef unsigned short u16;
typedef short bf16x8 __attribute__((ext_vector_type(8)));
typedef float f32x4  __attribute__((ext_vector_type(4)));

__device__ __forceinline__ float bf2f(u16 h) {
    return __uint_as_float(((unsigned int)h) << 16);
}
__device__ __forceinline__ u16 f2bf(float f) {
    unsigned int u = __float_as_uint(f);
    unsigned int r = u + 0x7FFFu + ((u >> 16) & 1u);   // round-to-nearest-even
    return (u16)(r >> 16);
}

// single prep kernel: all weight transposes+bf16 conversion + cnt zeroing, one launch
__global__ void prep_kernel(const float* __restrict__ l0w, const float* __restrict__ cw,
                            const float* __restrict__ l1w, u16* __restrict__ WT0,
                            u16* __restrict__ WTc, u16* __restrict__ WT1,
                            int* __restrict__ cnt) {
    int i = blockIdx.x * blockDim.x + threadIdx.x;
    if (i < 131072) {                       // 256*512
        int n = i >> 9, k = i & 511;
        WT0[i] = f2bf(l0w[(long)k * H_DIM + n]);
        return;
    }
    i -= 131072;
    if (i < 262144) {                       // 4*256*256
        int l = i >> 16, j = i & 65535, n = j >> 8, k = j & 255;
        WTc[(l << 16) + j] = f2bf(cw[(long)l * 65536 + (long)k * H_DIM + n]);
        return;
    }
    i -= 262144;
    if (i < 32768) {                        // 128*256
        int n = i >> 8, k = i & 255;
        WT1[i] = (n < C_OUT) ? f2bf(l1w[(long)k * C_OUT + n]) : (u16)0;
        return;
    }
    i -= 32768;
    if (i < N_NODES) cnt[i] = 0;            // CSR degree counter zeroing
}

// ---------------- CSR build ----------------
// 4 edges per thread via int4 (E_EDGES % 4 == 0)
__global__ void hist_kernel(const int* __restrict__ dst, int* __restrict__ deg) {
    int i = blockIdx.x * blockDim.x + threadIdx.x;
    if (i < E_EDGES / 4) {
        int4 d4 = reinterpret_cast<const int4*>(dst)[i];
        if (d4.x >= 0 && d4.x < N_NODES) atomicAdd(&deg[d4.x], 1);
        if (d4.y >= 0 && d4.y < N_NODES) atomicAdd(&deg[d4.y], 1);
        if (d4.z >= 0 && d4.z < N_NODES) atomicAdd(&deg[d4.z], 1);
        if (d4.w >= 0 && d4.w < N_NODES) atomicAdd(&deg[d4.w], 1);
    }
}

// single block, 1024 threads: exclusive scan; writes row_ptr AND seeds cnt with the
// row base so scatter's atomicAdd returns an absolute slot
__global__ void scan_kernel(int* cnt, int* __restrict__ row_ptr) {
    __shared__ int sums[1024];
    const int t = threadIdx.x;
    const int CH = (N_NODES + 1023) / 1024;   // 49
    const int base = t * CH;
    int s = 0;
    for (int i = 0; i < CH; ++i) {
        int idx = base + i;
        if (idx < N_NODES) s += cnt[idx];
    }
    sums[t] = s;
    __syncthreads();
    for (int off = 1; off < 1024; off <<= 1) {
        int v = (t >= off) ? sums[t - off] : 0;
        __syncthreads();
        sums[t] += v;
        __syncthreads();
    }
    int run = (t == 0) ? 0 : sums[t - 1];
    for (int i = 0; i < CH; ++i) {
        int idx = base + i;
        if (idx < N_NODES) {
            int dv = cnt[idx];
            row_ptr[idx] = run;
            cnt[idx] = run;     // seed for scatter
            run += dv;
        }
    }
    if (t == 1023) row_ptr[N_NODES] = run;    // == E
}

// 4 edges per thread via int4/float4
__global__ void scatter_kernel(const int* __restrict__ src, const int* __restrict__ dst,
                               const float* __restrict__ w,
                               int* __restrict__ cnt, int* __restrict__ s_src,
                               float* __restrict__ s_w) {
    int i = blockIdx.x * blockDim.x + threadIdx.x;
    if (i < E_EDGES / 4) {
        int4   s4 = reinterpret_cast<const int4*>(src)[i];
        int4   d4 = reinterpret_cast<const int4*>(dst)[i];
        float4 w4 = reinterpret_cast<const float4*>(w)[i];
        int   sv[4] = {s4.x, s4.y, s4.z, s4.w};
        int   dv[4] = {d4.x, d4.y, d4.z, d4.w};
        float wv[4] = {w4.x, w4.y, w4.z, w4.w};
        #pragma unroll
        for (int u = 0; u < 4; ++u) {
            int d = dv[u];
            if (d < 0) d = 0; if (d >= N_NODES) d = N_NODES - 1;   // defensive
            long idx = atomicAdd(&cnt[d], 1);                      // absolute slot
            if (idx < 0) idx = 0; if (idx >= E_EDGES) idx = E_EDGES - 1;  // defensive
            s_src[idx] = sv[u];
            s_w[idx]   = wv[u];
        }
    }
}

// ===== fused layer: gather(A@Xin) + combine -> LDS tile -> MFMA conv -> residual =====
// R21: + edge-meta LDS preload. Block's 16 rows own one contiguous CSR span
//   [row_ptr[bm], row_ptr[bm+16]) (mean 512 edges); bulk-coalesced into ms_src/ms_w
//   (MCAP=1280, global fallback for overflow). Gather meta reads become LDS
//   broadcasts -> removes the meta->X dependent global-load level.
//   LDS total 18.4 KB: FREE at 512 threads (thread limit 4 blocks/CU < LDS limit 8).
// Rest identical to R18/R20: 16 rows, 8 waves, 2 rows/wave, 4 gather chains in
//   flight, swizzled hs tile, 8-wave x 32-col conv MFMA, fused lin1 on LAST.
template <int LAST>
__global__ __launch_bounds__(512) void layer_kernel(
        const int* __restrict__ row_ptr, const int* __restrict__ s_src,
        const float* __restrict__ s_w, const u16* __restrict__ Xin,
        const u16* __restrict__ X0, u16* __restrict__ Xout,
        const u16* __restrict__ WT, float beta,
        const u16* __restrict__ WT1, const float* __restrict__ l1b,
        float* __restrict__ outp) {
    __shared__ __align__(16) u16 hs[16 * H_DIM];   // 8 KB, byte-swizzled
    __shared__ int   ms_src[MCAP];                 // 5 KB
    __shared__ float ms_w[MCAP];                   // 5 KB
    const int w  = threadIdx.x >> 6;   // 0..7
    const int l  = threadIdx.x & 63;
    const int hi = l >> 4, lo = l & 15;
    const int half = l >> 5;          // 0|1: which edge of the pair
    const int q    = l & 31;          // 16B chunk index within the 512B row
    const int bm = blockIdx.x * 16;

    // ---- phase 0: bulk-load this block's edge meta into LDS ----
    const int mbeg = row_ptr[bm];
    int mspan = row_ptr[bm + 16] - mbeg;
    if (mspan < 0) mspan = 0;
    const int mlim = (mspan < MCAP) ? mspan : MCAP;
    for (int j = threadIdx.x; j < mlim; j += 512) {
        long gj = (long)mbeg + j;
        if (gj >= 0 && gj < E_EDGES) { ms_src[j] = s_src[gj]; ms_w[j] = s_w[gj]; }
        else                         { ms_src[j] = 0;         ms_w[j] = 0.f; }
    }
    __syncthreads();

    // ---- phase 1: gather 2 rows per wave, 4 edges in flight ----
    for (int i = 0; i < 2; ++i) {
        const int rl  = w * 2 + i;
        const int row = bm + rl;
        int beg = row_ptr[row], end = row_ptr[row + 1];
        if (beg < 0) beg = 0; if (end > E_EDGES) end = E_EDGES;   // defensive
        float accA[8] = {}, accB[8] = {};
        for (int e = beg; e < end; e += 4) {
            const int eA = e + half;
            const int eB = e + 2 + half;
            const int cA = (eA < end) ? eA : end - 1;   // end-1 >= beg >= 0 here
            const int cB = (eB < end) ? eB : end - 1;
            const int rA = cA - mbeg;
            const int rB = cB - mbeg;
            int sA; float wA;
            int sB; float wB;
            if (rA >= 0 && rA < MCAP) { sA = ms_src[rA]; wA = ms_w[rA]; }
            else                      { sA = s_src[cA];  wA = s_w[cA]; }
            if (rB >= 0 && rB < MCAP) { sB = ms_src[rB]; wB = ms_w[rB]; }
            else                      { sB = s_src[cB];  wB = s_w[cB]; }
            if (eA >= end) wA = 0.f;
            if (eB >= end) wB = 0.f;
            if (sA < 0) sA = 0; if (sA >= N_NODES) sA = N_NODES - 1;  // defensive
            if (sB < 0) sB = 0; if (sB >= N_NODES) sB = N_NODES - 1;  // defensive
            bf16x8 vA = *reinterpret_cast<const bf16x8*>(Xin + (long)sA * H_DIM + q * 8);
            bf16x8 vB = *reinterpret_cast<const bf16x8*>(Xin + (long)sB * H_DIM + q * 8);
            #pragma unroll
            for (int j = 0; j < 8; ++j) {
                accA[j] += wA * bf2f((u16)vA[j]);
                accB[j] += wB * bf2f((u16)vB[j]);
            }
        }
        float acc[8];
        #pragma unroll
        for (int j = 0; j < 8; ++j) {
            float s = accA[j] + accB[j];
            s += __shfl_xor(s, 32);
            acc[j] = s;
        }
        if (l < 32) {
            bf16x8 x0 = *reinterpret_cast<const bf16x8*>(X0 + (long)row * H_DIM + q * 8);
            bf16x8 ov;
            #pragma unroll
            for (int j = 0; j < 8; ++j)
                ov[j] = (short)f2bf(0.5f * acc[j] + 0.5f * bf2f((u16)x0[j]));
            const int off = rl * 512 + ((q * 16) ^ ((rl & 7) << 4));   // 16B-aligned
            *reinterpret_cast<bf16x8*>((char*)hs + off) = ov;
        }
    }
    __syncthreads();

    // ---- phase 2: conv GEMM on the LDS tile (8 waves x 32 cols) ----
    const int col0 = w * 32;
    f32x4 acc[2];
    acc[0] = (f32x4){0.f, 0.f, 0.f, 0.f};
    acc[1] = (f32x4){0.f, 0.f, 0.f, 0.f};

    for (int k0 = 0; k0 < H_DIM; k0 += 32) {
        const int aoff = lo * 512 + (((k0 * 2) + hi * 16) ^ ((lo & 7) << 4));  // 16B-aligned
        bf16x8 a = *reinterpret_cast<const bf16x8*>((const char*)hs + aoff);
        #pragma unroll
        for (int t = 0; t < 2; ++t) {
            bf16x8 b = *reinterpret_cast<const bf16x8*>(
                    WT + (long)(col0 + t * 16 + lo) * H_DIM + k0 + hi * 8);
            acc[t] = __builtin_amdgcn_mfma_f32_16x16x32_bf16(a, b, acc[t], 0, 0, 0);
        }
    }

    if (LAST) __syncthreads();   // all phase-2 hs reads complete before in-place overwrite

    // ---- epilogue: residual + relu -> Xout (LAST: back into hs in place) ----
    #pragma unroll
    for (int t = 0; t < 2; ++t) {
        const int col = col0 + t * 16 + lo;
        #pragma unroll
        for (int r = 0; r < 4; ++r) {
            const int rl  = hi * 4 + r;
            const int row = bm + rl;
            const int hoff = rl * 512 + ((col * 2) ^ ((rl & 7) << 4));
            float hv = bf2f(*reinterpret_cast<const u16*>((const char*)hs + hoff));
            long idx = (long)row * H_DIM + col;
            float v = (1.f - beta) * hv + beta * acc[t][r] + bf2f(Xin[idx]);
            u16 vb = f2bf(fmaxf(v, 0.f));
            if (!LAST) {
                Xout[idx] = vb;
            } else {
                *reinterpret_cast<u16*>((char*)hs + hoff) = vb;   // slot owned by this thread
            }
        }
    }

    // ---- fused lin1 (last layer only): out = Xfinal @ WT1^T + l1b ----
    if (LAST) {
        __syncthreads();
        const int c1 = w * 16;
        f32x4 acc2 = (f32x4){0.f, 0.f, 0.f, 0.f};
        for (int k0 = 0; k0 < H_DIM; k0 += 32) {
            const int aoff = lo * 512 + (((k0 * 2) + hi * 16) ^ ((lo & 7) << 4));
            bf16x8 a = *reinterpret_cast<const bf16x8*>((const char*)hs + aoff);
            bf16x8 b = *reinterpret_cast<const bf16x8*>(
                    WT1 + (long)(c1 + lo) * H_DIM + k0 + hi * 8);
            acc2 = __builtin_amdgcn_mfma_f32_16x16x32_bf16(a, b, acc2, 0, 0, 0);
        }
        const int col = c1 + lo;
        if (col < C_OUT) {
            const float bias = l1b[col];
            #pragma unroll
            for (int r = 0; r < 4; ++r) {
                const int row = bm + hi * 4 + r;
                outp[(long)row * C_OUT + col] = acc2[r] + bias;
            }
        }
    }
}

// ---------------- lin0 (R21): M=32/block, 8 waves x 32 cols, B-frag reused over
// two row-halves -> WT0 L2 traffic halved. A fp32; X=X0=relu(acc+bias). ----------------
__global__ __launch_bounds__(512) void lin0_kernel(
        const float* __restrict__ Aptr, const u16* __restrict__ WT,
        const float* __restrict__ bias,
        u16* __restrict__ X, u16* __restrict__ X0) {
    const int w  = threadIdx.x >> 6;   // 0..7
    const int l  = threadIdx.x & 63;
    const int hi = l >> 4, lo = l & 15;
    const int bm = blockIdx.x * 32;
    const int col0 = w * 32;

    f32x4 acc[2][2];
    #pragma unroll
    for (int h = 0; h < 2; ++h)
        #pragma unroll
        for (int t = 0; t < 2; ++t) acc[h][t] = (f32x4){0.f, 0.f, 0.f, 0.f};

    for (int k0 = 0; k0 < F_INDIM; k0 += 32) {
        bf16x8 a[2];
        #pragma unroll
        for (int h = 0; h < 2; ++h) {
            const int grow = bm + h * 16 + lo;
            bf16x8 av = {0, 0, 0, 0, 0, 0, 0, 0};
            if (grow < N_NODES) {
                const float* ap = Aptr + (long)grow * F_INDIM + k0 + hi * 8;
                float4 f0 = *reinterpret_cast<const float4*>(ap);
                float4 f1 = *reinterpret_cast<const float4*>(ap + 4);
                av[0] = (short)f2bf(f0.x); av[1] = (short)f2bf(f0.y);
                av[2] = (short)f2bf(f0.z); av[3] = (short)f2bf(f0.w);
                av[4] = (short)f2bf(f1.x); av[5] = (short)f2bf(f1.y);
                av[6] = (short)f2bf(f1.z); av[7] = (short)f2bf(f1.w);
            }
            a[h] = av;
        }
        #pragma unroll
        for (int t = 0; t < 2; ++t) {
            bf16x8 b = *reinterpret_cast<const bf16x8*>(
                    WT + (long)(col0 + t * 16 + lo) * F_INDIM + k0 + hi * 8);
            acc[0][t] = __builtin_amdgcn_mfma_f32_16x16x32_bf16(a[0], b, acc[0][t], 0, 0, 0);
            acc[1][t] = __builtin_amdgcn_mfma_f32_16x16x32_bf16(a[1], b, acc[1][t], 0, 0, 0);
        }
    }

    #pragma unroll
    for (int h = 0; h < 2; ++h)
        #pragma unroll
        for (int t = 0; t < 2; ++t) {
            const int col = col0 + t * 16 + lo;
            #pragma unroll
            for (int r = 0; r < 4; ++r) {
                const int row = bm + h * 16 + hi * 4 + r;
                if (row < N_NODES) {
                    float v = fmaxf(acc[h][t][r] + bias[col], 0.f);
                    u16 hb = f2bf(v);
                    long idx = (long)row * H_DIM + col;
                    X[idx] = hb; X0[idx] = hb;
                }
            }
        }
}

extern "C" void kernel_launch(void* const* d_in, const int* in_sizes, int n_in,
                              void* d_out, int out_size, void* d_ws, size_t ws_size,
                              hipStream_t stream) {
    const float* x_in = (const float*)d_in[0];
    const int*   esrc = (const int*)d_in[1];
    const int*   edst = (const int*)d_in[2];
    const float* ew   = (const float*)d_in[3];
    const float* l0w  = (const float*)d_in[4];
    const float* l0b  = (const float*)d_in[5];
    const float* cw   = (const float*)d_in[6];
    const float* l1w  = (const float*)d_in[7];
    const float* l1b  = (const float*)d_in[8];
    float* out = (float*)d_out;
    (void)in_sizes; (void)n_in; (void)out_size;

    char* ws = (char*)d_ws;
    auto al = [](size_t x) { return (x + 255) & ~(size_t)255; };
    size_t o = 0;
    const size_t NHb = (size_t)N_NODES * H_DIM * sizeof(u16);    // 25.6 MB
    u16* Xa = (u16*)(ws + o);  o += al(NHb);
    u16* Xb = (u16*)(ws + o);  o += al(NHb);
    u16* X0 = (u16*)(ws + o);  o += al(NHb);
    int* row_ptr = (int*)(ws + o); o += al((N_NODES + 1) * sizeof(int));
    int* cnt     = (int*)(ws + o); o += al((size_t)N_NODES * sizeof(int));
    int* s_src   = (int*)(ws + o); o += al((size_t)E_EDGES * sizeof(int));
    float* s_w   = (float*)(ws + o); o += al((size_t)E_EDGES * sizeof(float));
    u16* WT0 = (u16*)(ws + o); o += al((size_t)H_DIM * F_INDIM * sizeof(u16));          // 256 KB
    u16* WTc = (u16*)(ws + o); o += al((size_t)L_LAYERS * H_DIM * H_DIM * sizeof(u16)); // 512 KB
    u16* WT1 = (u16*)(ws + o); o += al((size_t)128 * H_DIM * sizeof(u16));              // 64 KB
    if (ws_size < o) return;   // diagnostic: clean zero-output => ws too small

    const int MBLK = N_NODES / 16;   // 3125, exact

    // 0. weight prep + cnt zeroing (single launch)
    prep_kernel<<<1860, 256, 0, stream>>>(l0w, cw, l1w, WT0, WTc, WT1, cnt);

    // 1. input projection: Xa = X0 = relu(x_in @ l0w + l0b)   [MFMA, M=32 B-reuse]
    lin0_kernel<<<(N_NODES + 31) / 32, 512, 0, stream>>>(x_in, WT0, l0b, Xa, X0);

    // 2. CSR build (3 launches)
    hist_kernel<<<(E_EDGES / 4 + 255) / 256, 256, 0, stream>>>(edst, cnt);
    scan_kernel<<<1, 1024, 0, stream>>>(cnt, row_ptr);
    scatter_kernel<<<(E_EDGES / 4 + 255) / 256, 256, 0, stream>>>(esrc, edst, ew,
                                                                  cnt, s_src, s_w);

    // 3. fused layers, ping-pong Xa <-> Xb; last layer fuses lin1 (in-place hs reuse)
    u16* Xcur = Xa;
    u16* Xnxt = Xb;
    for (int l = 0; l < L_LAYERS - 1; ++l) {
        float beta = logf(1.0f / (float)(l + 1) + 1.0f);
        layer_kernel<0><<<MBLK, 512, 0, stream>>>(
            row_ptr, s_src, s_w, Xcur, X0, Xnxt,
            WTc + (size_t)l * H_DIM * H_DIM, beta,
            nullptr, nullptr, nullptr);
        u16* tmp = Xcur; Xcur = Xnxt; Xnxt = tmp;
    }
    {
        const int l = L_LAYERS - 1;
        float beta = logf(1.0f / (float)(l + 1) + 1.0f);
        layer_kernel<1><<<MBLK, 512, 0, stream>>>(
            row_ptr, s_src, s_w, Xcur, X0, nullptr,
            WTc + (size_t)l * H_DIM * H_DIM, beta,
            WT1, l1b, out);
    }
}

// Round 22
// 1037.200 us; speedup vs baseline: 1.1406x; 1.0264x over previous
//
#include <hip/hip_runtime.h>
#include <math.h>

#define N_NODES 50000
#define E_EDGES 1600000
#define F_INDIM 512
#define H_DIM   256
#define C_OUT   121
#define L_LAYERS 4
#define MCAP    1280   // per-block edge-meta LDS capacity

typedef unsigned short u16;
typedef short bf16x8 __attribute__((ext_vector_type(8)));
typedef float f32x4  __attribute__((ext_vector_type(4)));

__device__ __forceinline__ float bf2f(u16 h) {
    return __uint_as_float(((unsigned int)h) << 16);
}
__device__ __forceinline__ u16 f2bf(float f) {
    unsigned int u = __float_as_uint(f);
    unsigned int r = u + 0x7FFFu + ((u >> 16) & 1u);   // round-to-nearest-even
    return (u16)(r >> 16);
}

// single prep kernel: all weight transposes+bf16 conversion + cnt zeroing, one launch
__global__ void prep_kernel(const float* __restrict__ l0w, const float* __restrict__ cw,
                            const float* __restrict__ l1w, u16* __restrict__ WT0,
                            u16* __restrict__ WTc, u16* __restrict__ WT1,
                            int* __restrict__ cnt) {
    int i = blockIdx.x * blockDim.x + threadIdx.x;
    if (i < 131072) {                       // 256*512
        int n = i >> 9, k = i & 511;
        WT0[i] = f2bf(l0w[(long)k * H_DIM + n]);
        return;
    }
    i -= 131072;
    if (i < 262144) {                       // 4*256*256
        int l = i >> 16, j = i & 65535, n = j >> 8, k = j & 255;
        WTc[(l << 16) + j] = f2bf(cw[(long)l * 65536 + (long)k * H_DIM + n]);
        return;
    }
    i -= 262144;
    if (i < 32768) {                        // 128*256
        int n = i >> 8, k = i & 255;
        WT1[i] = (n < C_OUT) ? f2bf(l1w[(long)k * C_OUT + n]) : (u16)0;
        return;
    }
    i -= 32768;
    if (i < N_NODES) cnt[i] = 0;            // CSR degree counter zeroing
}

// x_in fp32 -> bf16, 8 elems/thread (float4 x2 -> bf16x8). Rounding identical to the
// in-register f2bf the old lin0 applied, so lin0 numerics are bit-unchanged.
__global__ void convx_kernel(const float* __restrict__ xin, u16* __restrict__ xbf) {
    long i = ((long)blockIdx.x * blockDim.x + threadIdx.x) * 8;
    if (i < (long)N_NODES * F_INDIM) {
        float4 f0 = *reinterpret_cast<const float4*>(xin + i);
        float4 f1 = *reinterpret_cast<const float4*>(xin + i + 4);
        bf16x8 v;
        v[0] = (short)f2bf(f0.x); v[1] = (short)f2bf(f0.y);
        v[2] = (short)f2bf(f0.z); v[3] = (short)f2bf(f0.w);
        v[4] = (short)f2bf(f1.x); v[5] = (short)f2bf(f1.y);
        v[6] = (short)f2bf(f1.z); v[7] = (short)f2bf(f1.w);
        *reinterpret_cast<bf16x8*>(xbf + i) = v;
    }
}

// ---------------- CSR build ----------------
// 4 edges per thread via int4 (E_EDGES % 4 == 0)
__global__ void hist_kernel(const int* __restrict__ dst, int* __restrict__ deg) {
    int i = blockIdx.x * blockDim.x + threadIdx.x;
    if (i < E_EDGES / 4) {
        int4 d4 = reinterpret_cast<const int4*>(dst)[i];
        if (d4.x >= 0 && d4.x < N_NODES) atomicAdd(&deg[d4.x], 1);
        if (d4.y >= 0 && d4.y < N_NODES) atomicAdd(&deg[d4.y], 1);
        if (d4.z >= 0 && d4.z < N_NODES) atomicAdd(&deg[d4.z], 1);
        if (d4.w >= 0 && d4.w < N_NODES) atomicAdd(&deg[d4.w], 1);
    }
}

// single block, 1024 threads: exclusive scan; writes row_ptr AND seeds cnt with the
// row base so scatter's atomicAdd returns an absolute slot
__global__ void scan_kernel(int* cnt, int* __restrict__ row_ptr) {
    __shared__ int sums[1024];
    const int t = threadIdx.x;
    const int CH = (N_NODES + 1023) / 1024;   // 49
    const int base = t * CH;
    int s = 0;
    for (int i = 0; i < CH; ++i) {
        int idx = base + i;
        if (idx < N_NODES) s += cnt[idx];
    }
    sums[t] = s;
    __syncthreads();
    for (int off = 1; off < 1024; off <<= 1) {
        int v = (t >= off) ? sums[t - off] : 0;
        __syncthreads();
        sums[t] += v;
        __syncthreads();
    }
    int run = (t == 0) ? 0 : sums[t - 1];
    for (int i = 0; i < CH; ++i) {
        int idx = base + i;
        if (idx < N_NODES) {
            int dv = cnt[idx];
            row_ptr[idx] = run;
            cnt[idx] = run;     // seed for scatter
            run += dv;
        }
    }
    if (t == 1023) row_ptr[N_NODES] = run;    // == E
}

// 4 edges per thread via int4/float4
__global__ void scatter_kernel(const int* __restrict__ src, const int* __restrict__ dst,
                               const float* __restrict__ w,
                               int* __restrict__ cnt, int* __restrict__ s_src,
                               float* __restrict__ s_w) {
    int i = blockIdx.x * blockDim.x + threadIdx.x;
    if (i < E_EDGES / 4) {
        int4   s4 = reinterpret_cast<const int4*>(src)[i];
        int4   d4 = reinterpret_cast<const int4*>(dst)[i];
        float4 w4 = reinterpret_cast<const float4*>(w)[i];
        int   sv[4] = {s4.x, s4.y, s4.z, s4.w};
        int   dv[4] = {d4.x, d4.y, d4.z, d4.w};
        float wv[4] = {w4.x, w4.y, w4.z, w4.w};
        #pragma unroll
        for (int u = 0; u < 4; ++u) {
            int d = dv[u];
            if (d < 0) d = 0; if (d >= N_NODES) d = N_NODES - 1;   // defensive
            long idx = atomicAdd(&cnt[d], 1);                      // absolute slot
            if (idx < 0) idx = 0; if (idx >= E_EDGES) idx = E_EDGES - 1;  // defensive
            s_src[idx] = sv[u];
            s_w[idx]   = wv[u];
        }
    }
}

// ===== fused layer (R21 form, unchanged): meta-preload + gather + MFMA + residual =====
template <int LAST>
__global__ __launch_bounds__(512) void layer_kernel(
        const int* __restrict__ row_ptr, const int* __restrict__ s_src,
        const float* __restrict__ s_w, const u16* __restrict__ Xin,
        const u16* __restrict__ X0, u16* __restrict__ Xout,
        const u16* __restrict__ WT, float beta,
        const u16* __restrict__ WT1, const float* __restrict__ l1b,
        float* __restrict__ outp) {
    __shared__ __align__(16) u16 hs[16 * H_DIM];   // 8 KB, byte-swizzled
    __shared__ int   ms_src[MCAP];                 // 5 KB
    __shared__ float ms_w[MCAP];                   // 5 KB
    const int w  = threadIdx.x >> 6;   // 0..7
    const int l  = threadIdx.x & 63;
    const int hi = l >> 4, lo = l & 15;
    const int half = l >> 5;          // 0|1: which edge of the pair
    const int q    = l & 31;          // 16B chunk index within the 512B row
    const int bm = blockIdx.x * 16;

    // ---- phase 0: bulk-load this block's edge meta into LDS ----
    const int mbeg = row_ptr[bm];
    int mspan = row_ptr[bm + 16] - mbeg;
    if (mspan < 0) mspan = 0;
    const int mlim = (mspan < MCAP) ? mspan : MCAP;
    for (int j = threadIdx.x; j < mlim; j += 512) {
        long gj = (long)mbeg + j;
        if (gj >= 0 && gj < E_EDGES) { ms_src[j] = s_src[gj]; ms_w[j] = s_w[gj]; }
        else                         { ms_src[j] = 0;         ms_w[j] = 0.f; }
    }
    __syncthreads();

    // ---- phase 1: gather 2 rows per wave, 4 edges in flight ----
    for (int i = 0; i < 2; ++i) {
        const int rl  = w * 2 + i;
        const int row = bm + rl;
        int beg = row_ptr[row], end = row_ptr[row + 1];
        if (beg < 0) beg = 0; if (end > E_EDGES) end = E_EDGES;   // defensive
        float accA[8] = {}, accB[8] = {};
        for (int e = beg; e < end; e += 4) {
            const int eA = e + half;
            const int eB = e + 2 + half;
            const int cA = (eA < end) ? eA : end - 1;   // end-1 >= beg >= 0 here
            const int cB = (eB < end) ? eB : end - 1;
            const int rA = cA - mbeg;
            const int rB = cB - mbeg;
            int sA; float wA;
            int sB; float wB;
            if (rA >= 0 && rA < MCAP) { sA = ms_src[rA]; wA = ms_w[rA]; }
            else                      { sA = s_src[cA];  wA = s_w[cA]; }
            if (rB >= 0 && rB < MCAP) { sB = ms_src[rB]; wB = ms_w[rB]; }
            else                      { sB = s_src[cB];  wB = s_w[cB]; }
            if (eA >= end) wA = 0.f;
            if (eB >= end) wB = 0.f;
            if (sA < 0) sA = 0; if (sA >= N_NODES) sA = N_NODES - 1;  // defensive
            if (sB < 0) sB = 0; if (sB >= N_NODES) sB = N_NODES - 1;  // defensive
            bf16x8 vA = *reinterpret_cast<const bf16x8*>(Xin + (long)sA * H_DIM + q * 8);
            bf16x8 vB = *reinterpret_cast<const bf16x8*>(Xin + (long)sB * H_DIM + q * 8);
            #pragma unroll
            for (int j = 0; j < 8; ++j) {
                accA[j] += wA * bf2f((u16)vA[j]);
                accB[j] += wB * bf2f((u16)vB[j]);
            }
        }
        float acc[8];
        #pragma unroll
        for (int j = 0; j < 8; ++j) {
            float s = accA[j] + accB[j];
            s += __shfl_xor(s, 32);
            acc[j] = s;
        }
        if (l < 32) {
            bf16x8 x0 = *reinterpret_cast<const bf16x8*>(X0 + (long)row * H_DIM + q * 8);
            bf16x8 ov;
            #pragma unroll
            for (int j = 0; j < 8; ++j)
                ov[j] = (short)f2bf(0.5f * acc[j] + 0.5f * bf2f((u16)x0[j]));
            const int off = rl * 512 + ((q * 16) ^ ((rl & 7) << 4));   // 16B-aligned
            *reinterpret_cast<bf16x8*>((char*)hs + off) = ov;
        }
    }
    __syncthreads();

    // ---- phase 2: conv GEMM on the LDS tile (8 waves x 32 cols) ----
    const int col0 = w * 32;
    f32x4 acc[2];
    acc[0] = (f32x4){0.f, 0.f, 0.f, 0.f};
    acc[1] = (f32x4){0.f, 0.f, 0.f, 0.f};

    for (int k0 = 0; k0 < H_DIM; k0 += 32) {
        const int aoff = lo * 512 + (((k0 * 2) + hi * 16) ^ ((lo & 7) << 4));  // 16B-aligned
        bf16x8 a = *reinterpret_cast<const bf16x8*>((const char*)hs + aoff);
        #pragma unroll
        for (int t = 0; t < 2; ++t) {
            bf16x8 b = *reinterpret_cast<const bf16x8*>(
                    WT + (long)(col0 + t * 16 + lo) * H_DIM + k0 + hi * 8);
            acc[t] = __builtin_amdgcn_mfma_f32_16x16x32_bf16(a, b, acc[t], 0, 0, 0);
        }
    }

    if (LAST) __syncthreads();   // all phase-2 hs reads complete before in-place overwrite

    // ---- epilogue: residual + relu -> Xout (LAST: back into hs in place) ----
    #pragma unroll
    for (int t = 0; t < 2; ++t) {
        const int col = col0 + t * 16 + lo;
        #pragma unroll
        for (int r = 0; r < 4; ++r) {
            const int rl  = hi * 4 + r;
            const int row = bm + rl;
            const int hoff = rl * 512 + ((col * 2) ^ ((rl & 7) << 4));
            float hv = bf2f(*reinterpret_cast<const u16*>((const char*)hs + hoff));
            long idx = (long)row * H_DIM + col;
            float v = (1.f - beta) * hv + beta * acc[t][r] + bf2f(Xin[idx]);
            u16 vb = f2bf(fmaxf(v, 0.f));
            if (!LAST) {
                Xout[idx] = vb;
            } else {
                *reinterpret_cast<u16*>((char*)hs + hoff) = vb;   // slot owned by this thread
            }
        }
    }

    // ---- fused lin1 (last layer only): out = Xfinal @ WT1^T + l1b ----
    if (LAST) {
        __syncthreads();
        const int c1 = w * 16;
        f32x4 acc2 = (f32x4){0.f, 0.f, 0.f, 0.f};
        for (int k0 = 0; k0 < H_DIM; k0 += 32) {
            const int aoff = lo * 512 + (((k0 * 2) + hi * 16) ^ ((lo & 7) << 4));
            bf16x8 a = *reinterpret_cast<const bf16x8*>((const char*)hs + aoff);
            bf16x8 b = *reinterpret_cast<const bf16x8*>(
                    WT1 + (long)(c1 + lo) * H_DIM + k0 + hi * 8);
            acc2 = __builtin_amdgcn_mfma_f32_16x16x32_bf16(a, b, acc2, 0, 0, 0);
        }
        const int col = c1 + lo;
        if (col < C_OUT) {
            const float bias = l1b[col];
            #pragma unroll
            for (int r = 0; r < 4; ++r) {
                const int row = bm + hi * 4 + r;
                outp[(long)row * C_OUT + col] = acc2[r] + bias;
            }
        }
    }
}

// ---------------- lin0 (R22): pure bf16 GEMM from pre-converted x_bf ----------------
// M=32/block, 8 waves x 32 cols, B-frag reused over two row-halves.
// A-frag = single 16B bf16x8 load (no fp32 convert chain -> deep load pipelining).
__global__ __launch_bounds__(512) void lin0_kernel(
        const u16* __restrict__ Abf, const u16* __restrict__ WT,
        const float* __restrict__ bias,
        u16* __restrict__ X, u16* __restrict__ X0) {
    const int w  = threadIdx.x >> 6;   // 0..7
    const int l  = threadIdx.x & 63;
    const int hi = l >> 4, lo = l & 15;
    const int bm = blockIdx.x * 32;
    const int col0 = w * 32;

    f32x4 acc[2][2];
    #pragma unroll
    for (int h = 0; h < 2; ++h)
        #pragma unroll
        for (int t = 0; t < 2; ++t) acc[h][t] = (f32x4){0.f, 0.f, 0.f, 0.f};

    for (int k0 = 0; k0 < F_INDIM; k0 += 32) {
        bf16x8 a[2];
        #pragma unroll
        for (int h = 0; h < 2; ++h) {
            const int grow = bm + h * 16 + lo;
            if (grow < N_NODES)
                a[h] = *reinterpret_cast<const bf16x8*>(
                        Abf + (long)grow * F_INDIM + k0 + hi * 8);
            else
                a[h] = (bf16x8){0, 0, 0, 0, 0, 0, 0, 0};
        }
        #pragma unroll
        for (int t = 0; t < 2; ++t) {
            bf16x8 b = *reinterpret_cast<const bf16x8*>(
                    WT + (long)(col0 + t * 16 + lo) * F_INDIM + k0 + hi * 8);
            acc[0][t] = __builtin_amdgcn_mfma_f32_16x16x32_bf16(a[0], b, acc[0][t], 0, 0, 0);
            acc[1][t] = __builtin_amdgcn_mfma_f32_16x16x32_bf16(a[1], b, acc[1][t], 0, 0, 0);
        }
    }

    #pragma unroll
    for (int h = 0; h < 2; ++h)
        #pragma unroll
        for (int t = 0; t < 2; ++t) {
            const int col = col0 + t * 16 + lo;
            #pragma unroll
            for (int r = 0; r < 4; ++r) {
                const int row = bm + h * 16 + hi * 4 + r;
                if (row < N_NODES) {
                    float v = fmaxf(acc[h][t][r] + bias[col], 0.f);
                    u16 hb = f2bf(v);
                    long idx = (long)row * H_DIM + col;
                    X[idx] = hb; X0[idx] = hb;
                }
            }
        }
}

extern "C" void kernel_launch(void* const* d_in, const int* in_sizes, int n_in,
                              void* d_out, int out_size, void* d_ws, size_t ws_size,
                              hipStream_t stream) {
    const float* x_in = (const float*)d_in[0];
    const int*   esrc = (const int*)d_in[1];
    const int*   edst = (const int*)d_in[2];
    const float* ew   = (const float*)d_in[3];
    const float* l0w  = (const float*)d_in[4];
    const float* l0b  = (const float*)d_in[5];
    const float* cw   = (const float*)d_in[6];
    const float* l1w  = (const float*)d_in[7];
    const float* l1b  = (const float*)d_in[8];
    float* out = (float*)d_out;
    (void)in_sizes; (void)n_in; (void)out_size;

    char* ws = (char*)d_ws;
    auto al = [](size_t x) { return (x + 255) & ~(size_t)255; };
    size_t o = 0;
    const size_t NHb = (size_t)N_NODES * H_DIM * sizeof(u16);    // 25.6 MB
    u16* Xa = (u16*)(ws + o);  o += al(NHb);
    u16* Xb = (u16*)(ws + o);  o += al(NHb);
    u16* X0 = (u16*)(ws + o);  o += al(NHb);
    int* row_ptr = (int*)(ws + o); o += al((N_NODES + 1) * sizeof(int));
    int* cnt     = (int*)(ws + o); o += al((size_t)N_NODES * sizeof(int));
    int* s_src   = (int*)(ws + o); o += al((size_t)E_EDGES * sizeof(int));
    float* s_w   = (float*)(ws + o); o += al((size_t)E_EDGES * sizeof(float));
    u16* WT0 = (u16*)(ws + o); o += al((size_t)H_DIM * F_INDIM * sizeof(u16));          // 256 KB
    u16* WTc = (u16*)(ws + o); o += al((size_t)L_LAYERS * H_DIM * H_DIM * sizeof(u16)); // 512 KB
    u16* WT1 = (u16*)(ws + o); o += al((size_t)128 * H_DIM * sizeof(u16));              // 64 KB
    u16* Xbf = (u16*)(ws + o); o += al((size_t)N_NODES * F_INDIM * sizeof(u16));        // 51.2 MB
    if (ws_size < o) return;   // diagnostic: clean zero-output => ws too small

    const int MBLK = N_NODES / 16;   // 3125, exact

    // 0. weight prep + cnt zeroing (single launch)
    prep_kernel<<<1860, 256, 0, stream>>>(l0w, cw, l1w, WT0, WTc, WT1, cnt);

    // 0b. x_in -> bf16 (memory-bound pass; rounding identical to old in-register cvt)
    convx_kernel<<<(N_NODES * F_INDIM / 8 + 255) / 256, 256, 0, stream>>>(x_in, Xbf);

    // 1. input projection: Xa = X0 = relu(x_bf @ l0w + l0b)   [pure bf16 MFMA]
    lin0_kernel<<<(N_NODES + 31) / 32, 512, 0, stream>>>(Xbf, WT0, l0b, Xa, X0);

    // 2. CSR build (3 launches)
    hist_kernel<<<(E_EDGES / 4 + 255) / 256, 256, 0, stream>>>(edst, cnt);
    scan_kernel<<<1, 1024, 0, stream>>>(cnt, row_ptr);
    scatter_kernel<<<(E_EDGES / 4 + 255) / 256, 256, 0, stream>>>(esrc, edst, ew,
                                                                  cnt, s_src, s_w);

    // 3. fused layers, ping-pong Xa <-> Xb; last layer fuses lin1 (in-place hs reuse)
    u16* Xcur = Xa;
    u16* Xnxt = Xb;
    for (int l = 0; l < L_LAYERS - 1; ++l) {
        float beta = logf(1.0f / (float)(l + 1) + 1.0f);
        layer_kernel<0><<<MBLK, 512, 0, stream>>>(
            row_ptr, s_src, s_w, Xcur, X0, Xnxt,
            WTc + (size_t)l * H_DIM * H_DIM, beta,
            nullptr, nullptr, nullptr);
        u16* tmp = Xcur; Xcur = Xnxt; Xnxt = tmp;
    }
    {
        const int l = L_LAYERS - 1;
        float beta = logf(1.0f / (float)(l + 1) + 1.0f);
        layer_kernel<1><<<MBLK, 512, 0, stream>>>(
            row_ptr, s_src, s_w, Xcur, X0, nullptr,
            WTc + (size_t)l * H_DIM * H_DIM, beta,
            WT1, l1b, out);
    }
}

// Round 23
// 1030.617 us; speedup vs baseline: 1.1479x; 1.0064x over previous
//
#include <hip/hip_runtime.h>
#include <math.h>

#define N_NODES 50000
#define E_EDGES 1600000
#define F_INDIM 512
#define H_DIM   256
#define C_OUT   121
#define L_LAYERS 4
#define MCAP    1280   // per-block edge-meta LDS capacity

typedef unsigned short u16;
typedef short bf16x8 __attribute__((ext_vector_type(8)));
typedef float f32x4  __attribute__((ext_vector_type(4)));

__device__ __forceinline__ float bf2f(u16 h) {
    return __uint_as_float(((unsigned int)h) << 16);
}
__device__ __forceinline__ u16 f2bf(float f) {
    unsigned int u = __float_as_uint(f);
    unsigned int r = u + 0x7FFFu + ((u >> 16) & 1u);   // round-to-nearest-even
    return (u16)(r >> 16);
}

// prep: weight transposes + bf16 conversion + cnt zeroing + x_in bf16 conversion
// (convx merged in R23: independent elementwise work, one launch)
__global__ void prep_kernel(const float* __restrict__ l0w, const float* __restrict__ cw,
                            const float* __restrict__ l1w, const float* __restrict__ xin,
                            u16* __restrict__ WT0, u16* __restrict__ WTc,
                            u16* __restrict__ WT1, int* __restrict__ cnt,
                            u16* __restrict__ xbf) {
    int i = blockIdx.x * blockDim.x + threadIdx.x;
    if (i < 131072) {                       // 256*512
        int n = i >> 9, k = i & 511;
        WT0[i] = f2bf(l0w[(long)k * H_DIM + n]);
        return;
    }
    i -= 131072;
    if (i < 262144) {                       // 4*256*256
        int l = i >> 16, j = i & 65535, n = j >> 8, k = j & 255;
        WTc[(l << 16) + j] = f2bf(cw[(long)l * 65536 + (long)k * H_DIM + n]);
        return;
    }
    i -= 262144;
    if (i < 32768) {                        // 128*256
        int n = i >> 8, k = i & 255;
        WT1[i] = (n < C_OUT) ? f2bf(l1w[(long)k * C_OUT + n]) : (u16)0;
        return;
    }
    i -= 32768;
    if (i < N_NODES) { cnt[i] = 0; return; }   // CSR degree counter zeroing
    i -= N_NODES;
    if (i < N_NODES * F_INDIM / 8) {           // x_in -> bf16, 8 elems/thread
        long b = (long)i * 8;
        float4 f0 = *reinterpret_cast<const float4*>(xin + b);
        float4 f1 = *reinterpret_cast<const float4*>(xin + b + 4);
        bf16x8 v;
        v[0] = (short)f2bf(f0.x); v[1] = (short)f2bf(f0.y);
        v[2] = (short)f2bf(f0.z); v[3] = (short)f2bf(f0.w);
        v[4] = (short)f2bf(f1.x); v[5] = (short)f2bf(f1.y);
        v[6] = (short)f2bf(f1.z); v[7] = (short)f2bf(f1.w);
        *reinterpret_cast<bf16x8*>(xbf + b) = v;
    }
}

// ---------------- CSR build ----------------
// 4 edges per thread via int4 (E_EDGES % 4 == 0)
__global__ void hist_kernel(const int* __restrict__ dst, int* __restrict__ deg) {
    int i = blockIdx.x * blockDim.x + threadIdx.x;
    if (i < E_EDGES / 4) {
        int4 d4 = reinterpret_cast<const int4*>(dst)[i];
        if (d4.x >= 0 && d4.x < N_NODES) atomicAdd(&deg[d4.x], 1);
        if (d4.y >= 0 && d4.y < N_NODES) atomicAdd(&deg[d4.y], 1);
        if (d4.z >= 0 && d4.z < N_NODES) atomicAdd(&deg[d4.z], 1);
        if (d4.w >= 0 && d4.w < N_NODES) atomicAdd(&deg[d4.w], 1);
    }
}

// single block, 1024 threads: exclusive scan; writes row_ptr AND seeds cnt with the
// row base so scatter's atomicAdd returns an absolute slot
__global__ void scan_kernel(int* cnt, int* __restrict__ row_ptr) {
    __shared__ int sums[1024];
    const int t = threadIdx.x;
    const int CH = (N_NODES + 1023) / 1024;   // 49
    const int base = t * CH;
    int s = 0;
    for (int i = 0; i < CH; ++i) {
        int idx = base + i;
        if (idx < N_NODES) s += cnt[idx];
    }
    sums[t] = s;
    __syncthreads();
    for (int off = 1; off < 1024; off <<= 1) {
        int v = (t >= off) ? sums[t - off] : 0;
        __syncthreads();
        sums[t] += v;
        __syncthreads();
    }
    int run = (t == 0) ? 0 : sums[t - 1];
    for (int i = 0; i < CH; ++i) {
        int idx = base + i;
        if (idx < N_NODES) {
            int dv = cnt[idx];
            row_ptr[idx] = run;
            cnt[idx] = run;     // seed for scatter
            run += dv;
        }
    }
    if (t == 1023) row_ptr[N_NODES] = run;    // == E
}

// 4 edges per thread; packed int2 (src, weight-bits) record -> one 8B scattered
// store per edge instead of two 4B stores to arrays 6.4MB apart (halves RMW lines)
__global__ void scatter_kernel(const int* __restrict__ src, const int* __restrict__ dst,
                               const float* __restrict__ w,
                               int* __restrict__ cnt, int2* __restrict__ eidx) {
    int i = blockIdx.x * blockDim.x + threadIdx.x;
    if (i < E_EDGES / 4) {
        int4   s4 = reinterpret_cast<const int4*>(src)[i];
        int4   d4 = reinterpret_cast<const int4*>(dst)[i];
        float4 w4 = reinterpret_cast<const float4*>(w)[i];
        int   sv[4] = {s4.x, s4.y, s4.z, s4.w};
        int   dv[4] = {d4.x, d4.y, d4.z, d4.w};
        float wv[4] = {w4.x, w4.y, w4.z, w4.w};
        #pragma unroll
        for (int u = 0; u < 4; ++u) {
            int d = dv[u];
            if (d < 0) d = 0; if (d >= N_NODES) d = N_NODES - 1;   // defensive
            long idx = atomicAdd(&cnt[d], 1);                      // absolute slot
            if (idx < 0) idx = 0; if (idx >= E_EDGES) idx = E_EDGES - 1;  // defensive
            eidx[idx] = make_int2(sv[u], __float_as_int(wv[u]));
        }
    }
}

// ===== fused layer (R21 structure; R23: int2 eidx meta) =====
template <int LAST>
__global__ __launch_bounds__(512) void layer_kernel(
        const int* __restrict__ row_ptr, const int2* __restrict__ eidx,
        const u16* __restrict__ Xin,
        const u16* __restrict__ X0, u16* __restrict__ Xout,
        const u16* __restrict__ WT, float beta,
        const u16* __restrict__ WT1, const float* __restrict__ l1b,
        float* __restrict__ outp) {
    __shared__ __align__(16) u16 hs[16 * H_DIM];   // 8 KB, byte-swizzled
    __shared__ int   ms_src[MCAP];                 // 5 KB
    __shared__ float ms_w[MCAP];                   // 5 KB
    const int w  = threadIdx.x >> 6;   // 0..7
    const int l  = threadIdx.x & 63;
    const int hi = l >> 4, lo = l & 15;
    const int half = l >> 5;          // 0|1: which edge of the pair
    const int q    = l & 31;          // 16B chunk index within the 512B row
    const int bm = blockIdx.x * 16;

    // ---- phase 0: bulk-load this block's edge meta into LDS (coalesced int2) ----
    const int mbeg = row_ptr[bm];
    int mspan = row_ptr[bm + 16] - mbeg;
    if (mspan < 0) mspan = 0;
    const int mlim = (mspan < MCAP) ? mspan : MCAP;
    for (int j = threadIdx.x; j < mlim; j += 512) {
        long gj = (long)mbeg + j;
        if (gj >= 0 && gj < E_EDGES) {
            int2 m = eidx[gj];
            ms_src[j] = m.x; ms_w[j] = __int_as_float(m.y);
        } else { ms_src[j] = 0; ms_w[j] = 0.f; }
    }
    __syncthreads();

    // ---- phase 1: gather 2 rows per wave, 4 edges in flight ----
    for (int i = 0; i < 2; ++i) {
        const int rl  = w * 2 + i;
        const int row = bm + rl;
        int beg = row_ptr[row], end = row_ptr[row + 1];
        if (beg < 0) beg = 0; if (end > E_EDGES) end = E_EDGES;   // defensive
        float accA[8] = {}, accB[8] = {};
        for (int e = beg; e < end; e += 4) {
            const int eA = e + half;
            const int eB = e + 2 + half;
            const int cA = (eA < end) ? eA : end - 1;   // end-1 >= beg >= 0 here
            const int cB = (eB < end) ? eB : end - 1;
            const int rA = cA - mbeg;
            const int rB = cB - mbeg;
            int sA; float wA;
            int sB; float wB;
            if (rA >= 0 && rA < MCAP) { sA = ms_src[rA]; wA = ms_w[rA]; }
            else { int2 m = eidx[cA]; sA = m.x; wA = __int_as_float(m.y); }
            if (rB >= 0 && rB < MCAP) { sB = ms_src[rB]; wB = ms_w[rB]; }
            else { int2 m = eidx[cB]; sB = m.x; wB = __int_as_float(m.y); }
            if (eA >= end) wA = 0.f;
            if (eB >= end) wB = 0.f;
            if (sA < 0) sA = 0; if (sA >= N_NODES) sA = N_NODES - 1;  // defensive
            if (sB < 0) sB = 0; if (sB >= N_NODES) sB = N_NODES - 1;  // defensive
            bf16x8 vA = *reinterpret_cast<const bf16x8*>(Xin + (long)sA * H_DIM + q * 8);
            bf16x8 vB = *reinterpret_cast<const bf16x8*>(Xin + (long)sB * H_DIM + q * 8);
            #pragma unroll
            for (int j = 0; j < 8; ++j) {
                accA[j] += wA * bf2f((u16)vA[j]);
                accB[j] += wB * bf2f((u16)vB[j]);
            }
        }
        float acc[8];
        #pragma unroll
        for (int j = 0; j < 8; ++j) {
            float s = accA[j] + accB[j];
            s += __shfl_xor(s, 32);
            acc[j] = s;
        }
        if (l < 32) {
            bf16x8 x0 = *reinterpret_cast<const bf16x8*>(X0 + (long)row * H_DIM + q * 8);
            bf16x8 ov;
            #pragma unroll
            for (int j = 0; j < 8; ++j)
                ov[j] = (short)f2bf(0.5f * acc[j] + 0.5f * bf2f((u16)x0[j]));
            const int off = rl * 512 + ((q * 16) ^ ((rl & 7) << 4));   // 16B-aligned
            *reinterpret_cast<bf16x8*>((char*)hs + off) = ov;
        }
    }
    __syncthreads();

    // ---- phase 2: conv GEMM on the LDS tile (8 waves x 32 cols) ----
    const int col0 = w * 32;
    f32x4 acc[2];
    acc[0] = (f32x4){0.f, 0.f, 0.f, 0.f};
    acc[1] = (f32x4){0.f, 0.f, 0.f, 0.f};

    for (int k0 = 0; k0 < H_DIM; k0 += 32) {
        const int aoff = lo * 512 + (((k0 * 2) + hi * 16) ^ ((lo & 7) << 4));  // 16B-aligned
        bf16x8 a = *reinterpret_cast<const bf16x8*>((const char*)hs + aoff);
        #pragma unroll
        for (int t = 0; t < 2; ++t) {
            bf16x8 b = *reinterpret_cast<const bf16x8*>(
                    WT + (long)(col0 + t * 16 + lo) * H_DIM + k0 + hi * 8);
            acc[t] = __builtin_amdgcn_mfma_f32_16x16x32_bf16(a, b, acc[t], 0, 0, 0);
        }
    }

    if (LAST) __syncthreads();   // all phase-2 hs reads complete before in-place overwrite

    // ---- epilogue: residual + relu -> Xout (LAST: back into hs in place) ----
    #pragma unroll
    for (int t = 0; t < 2; ++t) {
        const int col = col0 + t * 16 + lo;
        #pragma unroll
        for (int r = 0; r < 4; ++r) {
            const int rl  = hi * 4 + r;
            const int row = bm + rl;
            const int hoff = rl * 512 + ((col * 2) ^ ((rl & 7) << 4));
            float hv = bf2f(*reinterpret_cast<const u16*>((const char*)hs + hoff));
            long idx = (long)row * H_DIM + col;
            float v = (1.f - beta) * hv + beta * acc[t][r] + bf2f(Xin[idx]);
            u16 vb = f2bf(fmaxf(v, 0.f));
            if (!LAST) {
                Xout[idx] = vb;
            } else {
                *reinterpret_cast<u16*>((char*)hs + hoff) = vb;   // slot owned by this thread
            }
        }
    }

    // ---- fused lin1 (last layer only): out = Xfinal @ WT1^T + l1b ----
    if (LAST) {
        __syncthreads();
        const int c1 = w * 16;
        f32x4 acc2 = (f32x4){0.f, 0.f, 0.f, 0.f};
        for (int k0 = 0; k0 < H_DIM; k0 += 32) {
            const int aoff = lo * 512 + (((k0 * 2) + hi * 16) ^ ((lo & 7) << 4));
            bf16x8 a = *reinterpret_cast<const bf16x8*>((const char*)hs + aoff);
            bf16x8 b = *reinterpret_cast<const bf16x8*>(
                    WT1 + (long)(c1 + lo) * H_DIM + k0 + hi * 8);
            acc2 = __builtin_amdgcn_mfma_f32_16x16x32_bf16(a, b, acc2, 0, 0, 0);
        }
        const int col = c1 + lo;
        if (col < C_OUT) {
            const float bias = l1b[col];
            #pragma unroll
            for (int r = 0; r < 4; ++r) {
                const int row = bm + hi * 4 + r;
                outp[(long)row * C_OUT + col] = acc2[r] + bias;
            }
        }
    }
}

// ---------------- lin0 (R23): bf16 GEMM with explicit 2-stage register prefetch ----
// M=32/block, 8 waves x 32 cols. Next K-step's A/B fragments load BEFORE current
// MFMAs -> loads overlap matrix ops (defeats R21's minimal-VGPR serialization).
__global__ __launch_bounds__(512) void lin0_kernel(
        const u16* __restrict__ Abf, const u16* __restrict__ WT,
        const float* __restrict__ bias,
        u16* __restrict__ X, u16* __restrict__ X0) {
    const int w  = threadIdx.x >> 6;   // 0..7
    const int l  = threadIdx.x & 63;
    const int hi = l >> 4, lo = l & 15;
    const int bm = blockIdx.x * 32;
    const int col0 = w * 32;

    const int r0 = bm + lo;        // row for half 0 (always < N_NODES: 50000%32 handled below)
    const int r1 = bm + 16 + lo;   // row for half 1
    const bool v0 = r0 < N_NODES, v1 = r1 < N_NODES;
    const u16* a0p = Abf + (long)(v0 ? r0 : 0) * F_INDIM + hi * 8;
    const u16* a1p = Abf + (long)(v1 ? r1 : 0) * F_INDIM + hi * 8;
    const u16* b0p = WT + (long)(col0 + lo) * F_INDIM + hi * 8;
    const u16* b1p = WT + (long)(col0 + 16 + lo) * F_INDIM + hi * 8;

    f32x4 acc[2][2];
    #pragma unroll
    for (int h = 0; h < 2; ++h)
        #pragma unroll
        for (int t = 0; t < 2; ++t) acc[h][t] = (f32x4){0.f, 0.f, 0.f, 0.f};

    // stage 0 preload
    bf16x8 cA0 = *reinterpret_cast<const bf16x8*>(a0p);
    bf16x8 cA1 = *reinterpret_cast<const bf16x8*>(a1p);
    bf16x8 cB0 = *reinterpret_cast<const bf16x8*>(b0p);
    bf16x8 cB1 = *reinterpret_cast<const bf16x8*>(b1p);

    for (int k0 = 0; k0 < F_INDIM; k0 += 32) {
        bf16x8 nA0, nA1, nB0, nB1;
        if (k0 + 32 < F_INDIM) {
            nA0 = *reinterpret_cast<const bf16x8*>(a0p + k0 + 32);
            nA1 = *reinterpret_cast<const bf16x8*>(a1p + k0 + 32);
            nB0 = *reinterpret_cast<const bf16x8*>(b0p + k0 + 32);
            nB1 = *reinterpret_cast<const bf16x8*>(b1p + k0 + 32);
        }
        bf16x8 uA0 = v0 ? cA0 : (bf16x8){0,0,0,0,0,0,0,0};
        bf16x8 uA1 = v1 ? cA1 : (bf16x8){0,0,0,0,0,0,0,0};
        acc[0][0] = __builtin_amdgcn_mfma_f32_16x16x32_bf16(uA0, cB0, acc[0][0], 0, 0, 0);
        acc[1][0] = __builtin_amdgcn_mfma_f32_16x16x32_bf16(uA1, cB0, acc[1][0], 0, 0, 0);
        acc[0][1] = __builtin_amdgcn_mfma_f32_16x16x32_bf16(uA0, cB1, acc[0][1], 0, 0, 0);
        acc[1][1] = __builtin_amdgcn_mfma_f32_16x16x32_bf16(uA1, cB1, acc[1][1], 0, 0, 0);
        cA0 = nA0; cA1 = nA1; cB0 = nB0; cB1 = nB1;
    }

    #pragma unroll
    for (int h = 0; h < 2; ++h)
        #pragma unroll
        for (int t = 0; t < 2; ++t) {
            const int col = col0 + t * 16 + lo;
            #pragma unroll
            for (int r = 0; r < 4; ++r) {
                const int row = bm + h * 16 + hi * 4 + r;
                if (row < N_NODES) {
                    float v = fmaxf(acc[h][t][r] + bias[col], 0.f);
                    u16 hb = f2bf(v);
                    long idx = (long)row * H_DIM + col;
                    X[idx] = hb; X0[idx] = hb;
                }
            }
        }
}

extern "C" void kernel_launch(void* const* d_in, const int* in_sizes, int n_in,
                              void* d_out, int out_size, void* d_ws, size_t ws_size,
                              hipStream_t stream) {
    const float* x_in = (const float*)d_in[0];
    const int*   esrc = (const int*)d_in[1];
    const int*   edst = (const int*)d_in[2];
    const float* ew   = (const float*)d_in[3];
    const float* l0w  = (const float*)d_in[4];
    const float* l0b  = (const float*)d_in[5];
    const float* cw   = (const float*)d_in[6];
    const float* l1w  = (const float*)d_in[7];
    const float* l1b  = (const float*)d_in[8];
    float* out = (float*)d_out;
    (void)in_sizes; (void)n_in; (void)out_size;

    char* ws = (char*)d_ws;
    auto al = [](size_t x) { return (x + 255) & ~(size_t)255; };
    size_t o = 0;
    const size_t NHb = (size_t)N_NODES * H_DIM * sizeof(u16);    // 25.6 MB
    u16* Xa = (u16*)(ws + o);  o += al(NHb);
    u16* Xb = (u16*)(ws + o);  o += al(NHb);
    u16* X0 = (u16*)(ws + o);  o += al(NHb);
    int* row_ptr = (int*)(ws + o); o += al((N_NODES + 1) * sizeof(int));
    int* cnt     = (int*)(ws + o); o += al((size_t)N_NODES * sizeof(int));
    int2* eidx   = (int2*)(ws + o); o += al((size_t)E_EDGES * sizeof(int2));            // 12.8 MB
    u16* WT0 = (u16*)(ws + o); o += al((size_t)H_DIM * F_INDIM * sizeof(u16));          // 256 KB
    u16* WTc = (u16*)(ws + o); o += al((size_t)L_LAYERS * H_DIM * H_DIM * sizeof(u16)); // 512 KB
    u16* WT1 = (u16*)(ws + o); o += al((size_t)128 * H_DIM * sizeof(u16));              // 64 KB
    u16* Xbf = (u16*)(ws + o); o += al((size_t)N_NODES * F_INDIM * sizeof(u16));        // 51.2 MB
    if (ws_size < o) return;   // diagnostic: clean zero-output => ws too small

    const int MBLK = N_NODES / 16;   // 3125, exact

    // 0. prep: weights + cnt zero + x_in bf16 (single launch: 3.68M elems -> 14375 blocks)
    {
        const long total = 131072L + 262144 + 32768 + N_NODES + (long)N_NODES * F_INDIM / 8;
        prep_kernel<<<(int)((total + 255) / 256), 256, 0, stream>>>(
            l0w, cw, l1w, x_in, WT0, WTc, WT1, cnt, Xbf);
    }

    // 1. input projection: Xa = X0 = relu(x_bf @ l0w + l0b)   [bf16 MFMA, prefetched]
    lin0_kernel<<<(N_NODES + 31) / 32, 512, 0, stream>>>(Xbf, WT0, l0b, Xa, X0);

    // 2. CSR build (3 launches)
    hist_kernel<<<(E_EDGES / 4 + 255) / 256, 256, 0, stream>>>(edst, cnt);
    scan_kernel<<<1, 1024, 0, stream>>>(cnt, row_ptr);
    scatter_kernel<<<(E_EDGES / 4 + 255) / 256, 256, 0, stream>>>(esrc, edst, ew,
                                                                  cnt, eidx);

    // 3. fused layers, ping-pong Xa <-> Xb; last layer fuses lin1 (in-place hs reuse)
    u16* Xcur = Xa;
    u16* Xnxt = Xb;
    for (int l = 0; l < L_LAYERS - 1; ++l) {
        float beta = logf(1.0f / (float)(l + 1) + 1.0f);
        layer_kernel<0><<<MBLK, 512, 0, stream>>>(
            row_ptr, eidx, Xcur, X0, Xnxt,
            WTc + (size_t)l * H_DIM * H_DIM, beta,
            nullptr, nullptr, nullptr);
        u16* tmp = Xcur; Xcur = Xnxt; Xnxt = tmp;
    }
    {
        const int l = L_LAYERS - 1;
        float beta = logf(1.0f / (float)(l + 1) + 1.0f);
        layer_kernel<1><<<MBLK, 512, 0, stream>>>(
            row_ptr, eidx, Xcur, X0, nullptr,
            WTc + (size_t)l * H_DIM * H_DIM, beta,
            WT1, l1b, out);
    }
}